// Round 2
// baseline (15603.183 us; speedup 1.0000x reference)
//
#include <hip/hip_runtime.h>
#include <hip/hip_bf16.h>

#define NN 20000   // nodes
#define NE 320000  // edges
#define NB 64      // graphs
#define DIN 16
#define DE 8
#define HE 128
#define D 32
#define TST 8
#define S2S 12

__device__ __forceinline__ float sigf(float x) { return 1.f / (1.f + expf(-x)); }

__device__ __forceinline__ void store8(float* p, const float* v) {
    *(float4*)p = *(const float4*)v;
    *(float4*)(p + 4) = *(const float4*)(v + 4);
}
__device__ __forceinline__ void store8(unsigned short* p, const float* v) {
    unsigned short s[8];
#pragma unroll
    for (int j = 0; j < 8; ++j) {
        __hip_bfloat16 b = __float2bfloat16(v[j]);
        s[j] = *(unsigned short*)&b;
    }
    *(uint4*)p = *(const uint4*)s;  // 16B aligned: offsets are multiples of 16 bf16
}
__device__ __forceinline__ void unpack2(unsigned u, float& lo, float& hi) {
    lo = __uint_as_float(u << 16);
    hi = __uint_as_float(u & 0xffff0000u);
}

// -------- graph segment starts: start[b] = lower_bound(batch, b), start[NB]=NN
__global__ void k_graph_start(const int* __restrict__ batch, int* __restrict__ start) {
    int b = threadIdx.x;
    if (b > NB) return;
    int lo = 0, hi = NN;
    while (lo < hi) {
        int mid = (lo + hi) >> 1;
        if (batch[mid] < b) lo = mid + 1; else hi = mid;
    }
    start[b] = lo;
}

// -------- h0 = x @ W_in + b_in
__global__ __launch_bounds__(256) void k_input_linear(
    const float* __restrict__ x, const float* __restrict__ Win,
    const float* __restrict__ bin, float* __restrict__ h) {
    int idx = blockIdx.x * 256 + threadIdx.x;  // n*32+f, grid exact
    int n = idx >> 5, f = idx & 31;
    float acc = bin[f];
#pragma unroll
    for (int d = 0; d < DIN; ++d) acc += x[n * DIN + d] * Win[d * D + f];
    h[idx] = acc;
}

// -------- A[e, d*32+f] = (relu(ed@We1+be1) @ We2 + be2)
// block: 64 edges x 128 f-cols, 256 threads, 4x8 micro-tile. LDS ~55 KB.
template <typename AT>
__global__ __launch_bounds__(256) void k_edge_net(
    const float* __restrict__ ed, const float* __restrict__ We1,
    const float* __restrict__ be1, const float* __restrict__ We2,
    const float* __restrict__ be2, AT* __restrict__ A) {
    const int tid = threadIdx.x;
    const int e0 = blockIdx.x * 64;
    const int f0 = blockIdx.y * 128;

    __shared__ float eds[64][9];     // 2.3 KB (pad kills conflicts)
    __shared__ float we1s[DE * HE];  // 4 KB
    __shared__ float be1s[HE];       // 0.5 KB
    __shared__ float zs[HE][64];     // 32 KB  z[k][e_local]
    __shared__ float wsm[32][128];   // 16 KB  We2 k-chunk

    for (int i = tid; i < 64 * DE; i += 256) eds[i >> 3][i & 7] = ed[(size_t)e0 * DE + i];
    for (int i = tid; i < DE * HE; i += 256) we1s[i] = We1[i];
    if (tid < HE) be1s[tid] = be1[tid];
    __syncthreads();

    {   // z phase: thread -> (e = tid&63, k-block = tid>>6)
        const int e = tid & 63, kb = tid >> 6;
        float edr[8];
#pragma unroll
        for (int j = 0; j < 8; ++j) edr[j] = eds[e][j];
        for (int m = 0; m < 32; ++m) {
            const int k = kb * 32 + m;
            float acc = be1s[k];
#pragma unroll
            for (int j = 0; j < 8; ++j) acc += edr[j] * we1s[j * HE + k];
            zs[k][e] = fmaxf(acc, 0.f);
        }
    }
    __syncthreads();

    const int fg = tid & 15, eg = tid >> 4;  // e = eg*4+i, f = fg*8+j
    float acc[4][8];
#pragma unroll
    for (int i = 0; i < 4; ++i)
#pragma unroll
        for (int j = 0; j < 8; ++j) acc[i][j] = 0.f;

    for (int kc = 0; kc < 4; ++kc) {
#pragma unroll
        for (int r = 0; r < 4; ++r) {  // stage We2[kc*32..+32)[f0..f0+128) as float4
            const int idx4 = tid + 256 * r;        // 0..1023
            const int kr = idx4 >> 5, f4 = idx4 & 31;
            *(float4*)(&wsm[kr][f4 * 4]) =
                *(const float4*)(We2 + (size_t)(kc * 32 + kr) * 1024 + f0 + f4 * 4);
        }
        __syncthreads();
#pragma unroll 8
        for (int kr = 0; kr < 32; ++kr) {
            float zr[4], wr[8];
#pragma unroll
            for (int i = 0; i < 4; ++i) zr[i] = zs[kc * 32 + kr][eg * 4 + i];
            *(float4*)wr = *(const float4*)&wsm[kr][fg * 8];
            *(float4*)(wr + 4) = *(const float4*)&wsm[kr][fg * 8 + 4];
#pragma unroll
            for (int i = 0; i < 4; ++i)
#pragma unroll
                for (int j = 0; j < 8; ++j) acc[i][j] += zr[i] * wr[j];
        }
        __syncthreads();
    }

    float b2[8];
#pragma unroll
    for (int j = 0; j < 8; ++j) b2[j] = be2[f0 + fg * 8 + j];
#pragma unroll
    for (int i = 0; i < 4; ++i) {
        const int e = e0 + eg * 4 + i;
        float v[8];
#pragma unroll
        for (int j = 0; j < 8; ++j) v[j] = acc[i][j] + b2[j];
        store8(A + (size_t)e * 1024 + f0 + fg * 8, v);
    }
}

// -------- msg_e = h[src_e] . A_e ; agg[dst_e] += msg  (fp32 A, float4 loads)
// block: 32 edges, 8 threads/edge (thread = 4 consecutive f)
__global__ __launch_bounds__(256) void k_msg_f32(
    const float* __restrict__ A, const float* __restrict__ h,
    const int* __restrict__ src, const int* __restrict__ dst,
    float* __restrict__ agg) {
    const int tid = threadIdx.x, e0 = blockIdx.x * 32;
    __shared__ float hs[32][33];
    __shared__ int dsts[32];
    if (tid < 32) dsts[tid] = dst[e0 + tid];
    for (int i = tid; i < 32 * 32; i += 256) {
        const int e = i >> 5, d = i & 31;
        hs[e][d] = h[(size_t)src[e0 + e] * D + d];
    }
    __syncthreads();
    const int e = tid >> 3, fq = tid & 7;
    const float* Ae = A + (size_t)(e0 + e) * 1024 + fq * 4;
    float4 acc = {0.f, 0.f, 0.f, 0.f};
#pragma unroll
    for (int d = 0; d < 32; ++d) {
        const float4 a4 = *(const float4*)(Ae + (size_t)d * 32);
        const float hd = hs[e][d];
        acc.x += hd * a4.x; acc.y += hd * a4.y; acc.z += hd * a4.z; acc.w += hd * a4.w;
    }
    float* ap = &agg[(size_t)dsts[e] * D + fq * 4];
    atomicAdd(ap, acc.x); atomicAdd(ap + 1, acc.y);
    atomicAdd(ap + 2, acc.z); atomicAdd(ap + 3, acc.w);
}

// -------- same, bf16 A (uint4 = 8 bf16 per load). block: 64 edges, 4 thr/edge
__global__ __launch_bounds__(256) void k_msg_bf16(
    const unsigned short* __restrict__ A, const float* __restrict__ h,
    const int* __restrict__ src, const int* __restrict__ dst,
    float* __restrict__ agg) {
    const int tid = threadIdx.x, e0 = blockIdx.x * 64;
    __shared__ float hs[64][33];
    __shared__ int dsts[64];
    if (tid < 64) dsts[tid] = dst[e0 + tid];
    for (int i = tid; i < 64 * 32; i += 256) {
        const int e = i >> 5, d = i & 31;
        hs[e][d] = h[(size_t)src[e0 + e] * D + d];
    }
    __syncthreads();
    const int e = tid >> 2, fo = tid & 3;  // f = fo*8 .. +8
    const unsigned short* Ae = A + (size_t)(e0 + e) * 1024 + fo * 8;
    float acc[8];
#pragma unroll
    for (int j = 0; j < 8; ++j) acc[j] = 0.f;
#pragma unroll
    for (int d = 0; d < 32; ++d) {
        const uint4 v = *(const uint4*)(Ae + (size_t)d * 32);
        const float hd = hs[e][d];
        float lo, hi;
        unpack2(v.x, lo, hi); acc[0] += hd * lo; acc[1] += hd * hi;
        unpack2(v.y, lo, hi); acc[2] += hd * lo; acc[3] += hd * hi;
        unpack2(v.z, lo, hi); acc[4] += hd * lo; acc[5] += hd * hi;
        unpack2(v.w, lo, hi); acc[6] += hd * lo; acc[7] += hd * hi;
    }
    float* ap = &agg[(size_t)dsts[e] * D + fo * 8];
#pragma unroll
    for (int j = 0; j < 8; ++j) atomicAdd(ap + j, acc[j]);
}

// -------- fused fallback: recompute z per edge, bilinear msg without A buffer
// block: 64 edges, thread = (edge-pair ep, f-quad fg). LDS ~63 KB.
__global__ __launch_bounds__(256) void k_msg_fused(
    const float* __restrict__ ed, const float* __restrict__ We1,
    const float* __restrict__ be1, const float* __restrict__ We2,
    const float* __restrict__ h, const int* __restrict__ src,
    const int* __restrict__ dst, float* __restrict__ agg) {
    const int tid = threadIdx.x;
    const int e0 = blockIdx.x * 64;
    __shared__ float we1s[DE * HE];   // 4 KB
    __shared__ float be1s[HE];        // 0.5 KB
    __shared__ float eds[64][9];      // 2.3 KB
    __shared__ float zs[HE][64];      // 32 KB
    __shared__ float hs[64][33];      // 8.4 KB
    __shared__ float ws2s[4][1024];   // 16 KB
    __shared__ int srcs[64];

    for (int i = tid; i < DE * HE; i += 256) we1s[i] = We1[i];
    if (tid < HE) be1s[tid] = be1[tid];
    if (tid < 64) srcs[tid] = src[e0 + tid];
    for (int i = tid; i < 64 * DE; i += 256) eds[i >> 3][i & 7] = ed[(size_t)e0 * DE + i];
    __syncthreads();

    {   // z phase
        const int e = tid & 63, kb = tid >> 6;
        float edr[8];
#pragma unroll
        for (int j = 0; j < 8; ++j) edr[j] = eds[e][j];
        for (int m = 0; m < 32; ++m) {
            const int k = kb * 32 + m;
            float acc = be1s[k];
#pragma unroll
            for (int j = 0; j < 8; ++j) acc += edr[j] * we1s[j * HE + k];
            zs[k][e] = fmaxf(acc, 0.f);
        }
    }
    for (int i = tid; i < 64 * 32; i += 256) {
        const int e = i >> 5, d = i & 31;
        hs[e][d] = h[(size_t)srcs[e] * D + d];
    }
    __syncthreads();

    const int ep = tid & 31, fg = tid >> 5;  // edges 2ep,2ep+1 ; f = fg*4..+4
    float hr[2][32];
#pragma unroll
    for (int d = 0; d < 32; ++d) {
        hr[0][d] = hs[ep * 2][d];
        hr[1][d] = hs[ep * 2 + 1][d];
    }
    float acc[2][4];
#pragma unroll
    for (int i = 0; i < 2; ++i)
#pragma unroll
        for (int j = 0; j < 4; ++j) acc[i][j] = 0.f;

    for (int kc = 0; kc < 32; ++kc) {
        __syncthreads();  // protect ws2s rewrite vs previous chunk's reads
#pragma unroll
        for (int r = 0; r < 4; ++r) {  // stage We2 rows kc*4..+4 (4096 floats)
            const int idx4 = tid + 256 * r;  // 0..1023
            const int kr = idx4 >> 8, c4 = idx4 & 255;
            *(float4*)&ws2s[kr][c4 * 4] =
                *(const float4*)(We2 + (size_t)(kc * 4 + kr) * 1024 + c4 * 4);
        }
        __syncthreads();
#pragma unroll
        for (int kk = 0; kk < 4; ++kk) {
            const int k = kc * 4 + kk;
            const float z0 = zs[k][ep * 2], z1 = zs[k][ep * 2 + 1];
#pragma unroll
            for (int d = 0; d < 32; ++d) {
                const float4 w4 = *(const float4*)&ws2s[kk][d * 32 + fg * 4];
                const float c0 = z0 * hr[0][d], c1 = z1 * hr[1][d];
                acc[0][0] += c0 * w4.x; acc[0][1] += c0 * w4.y;
                acc[0][2] += c0 * w4.z; acc[0][3] += c0 * w4.w;
                acc[1][0] += c1 * w4.x; acc[1][1] += c1 * w4.y;
                acc[1][2] += c1 * w4.z; acc[1][3] += c1 * w4.w;
            }
        }
    }
#pragma unroll
    for (int i = 0; i < 2; ++i) {
        const int e = e0 + ep * 2 + i;
        float* ap = &agg[(size_t)dst[e] * D + fg * 4];
#pragma unroll
        for (int j = 0; j < 4; ++j) atomicAdd(ap + j, acc[i][j]);
    }
}

// -------- GRU cell per node (8 nodes x 32 f per block)
__global__ __launch_bounds__(256) void k_gru(
    const float* __restrict__ h, const float* __restrict__ agg,
    const float* __restrict__ Wroot, const float* __restrict__ bconv,
    const float* __restrict__ Wih, const float* __restrict__ Whh,
    const float* __restrict__ bih, const float* __restrict__ bhh,
    float* __restrict__ hout) {
    const int idx = blockIdx.x * 256 + threadIdx.x;  // grid exact: NN*D/256
    const int n = idx >> 5, f = idx & 31, nl = threadIdx.x >> 5;
    __shared__ float hsh[8][33], msh[8][33];
    const float hv = h[n * D + f];
    hsh[nl][f] = hv;
    __syncthreads();
    float m = bconv[f] + agg[n * D + f];
#pragma unroll
    for (int d = 0; d < 32; ++d) m += hsh[nl][d] * Wroot[d * D + f];
    m = fmaxf(m, 0.f);
    msh[nl][f] = m;
    __syncthreads();
    float gir = bih[f], giz = bih[D + f], gin = bih[2 * D + f];
    float ghr = bhh[f], ghz = bhh[D + f], ghn = bhh[2 * D + f];
#pragma unroll
    for (int d = 0; d < 32; ++d) {
        const float md = msh[nl][d], hd = hsh[nl][d];
        gir += md * Wih[f * D + d];
        giz += md * Wih[(D + f) * D + d];
        gin += md * Wih[(2 * D + f) * D + d];
        ghr += hd * Whh[f * D + d];
        ghz += hd * Whh[(D + f) * D + d];
        ghn += hd * Whh[(2 * D + f) * D + d];
    }
    const float r = sigf(gir + ghr);
    const float z = sigf(giz + ghz);
    const float nn2 = tanhf(gin + r * ghn);
    hout[n * D + f] = (1.f - z) * nn2 + z * hv;
}

// -------- one Set2Set step: LSTM cell + segment softmax attention, block = graph
__global__ __launch_bounds__(256) void k_s2s(
    const float* __restrict__ h, const int* __restrict__ start,
    float* __restrict__ qstar, float* __restrict__ hl, float* __restrict__ cl,
    const float* __restrict__ Wih, const float* __restrict__ Whh,
    const float* __restrict__ bih, const float* __restrict__ bhh,
    float* __restrict__ ebuf) {
    const int b = blockIdx.x, t = threadIdx.x;
    __shared__ float qst[64], hls[32], gates[128], qs[32];
    __shared__ float red[256];
    __shared__ float rsum[8][33];
    if (t < 64) qst[t] = qstar[b * 64 + t];
    if (t < 32) hls[t] = hl[b * 32 + t];
    __syncthreads();
    if (t < 128) {
        float g = bih[t] + bhh[t];
#pragma unroll 8
        for (int j = 0; j < 64; ++j) g += qst[j] * Wih[t * 64 + j];
#pragma unroll 8
        for (int j = 0; j < 32; ++j) g += hls[j] * Whh[t * 32 + j];
        gates[t] = g;
    }
    __syncthreads();
    if (t < 32) {  // i,f,g,o order
        const float ig = sigf(gates[t]);
        const float fg = sigf(gates[32 + t]);
        const float gg = tanhf(gates[64 + t]);
        const float og = sigf(gates[96 + t]);
        const float c = fg * cl[b * 32 + t] + ig * gg;
        const float q = og * tanhf(c);
        cl[b * 32 + t] = c;
        hl[b * 32 + t] = q;
        qstar[b * 64 + t] = q;
        qs[t] = q;
    }
    __syncthreads();
    const int s0 = start[b], s1 = start[b + 1];
    float lmax = -3.4e38f;
    for (int n = s0 + t; n < s1; n += 256) {
        const float4* hv = (const float4*)(h + (size_t)n * D);
        float e = 0.f;
#pragma unroll
        for (int u = 0; u < 8; ++u) {
            const float4 v = hv[u];
            e += v.x * qs[u * 4] + v.y * qs[u * 4 + 1] + v.z * qs[u * 4 + 2] + v.w * qs[u * 4 + 3];
        }
        ebuf[n] = e;
        lmax = fmaxf(lmax, e);
    }
    red[t] = lmax;
    __syncthreads();
    for (int s = 128; s > 0; s >>= 1) {
        if (t < s) red[t] = fmaxf(red[t], red[t + s]);
        __syncthreads();
    }
    const float smax = red[0];
    __syncthreads();
    float lsum = 0.f;
    for (int n = s0 + t; n < s1; n += 256) {
        const float w = expf(ebuf[n] - smax);
        ebuf[n] = w;
        lsum += w;
    }
    red[t] = lsum;
    __syncthreads();
    for (int s = 128; s > 0; s >>= 1) {
        if (t < s) red[t] += red[t + s];
        __syncthreads();
    }
    const float den = red[0];
    const float inv = (den > 0.f) ? 1.f / den : 0.f;
    const int fl = t & 31, sl = t >> 5;
    float racc = 0.f;
    for (int n = s0 + sl; n < s1; n += 8) racc += ebuf[n] * h[(size_t)n * D + fl];
    rsum[sl][fl] = racc;
    __syncthreads();
    if (sl == 0) {
        float rv = 0.f;
#pragma unroll
        for (int u = 0; u < 8; ++u) rv += rsum[u][fl];
        qstar[b * 64 + 32 + fl] = rv * inv;
    }
}

// -------- out = q_star @ W_out + b_out
__global__ void k_out(const float* __restrict__ qstar, const float* __restrict__ Wout,
                      const float* __restrict__ bout, float* __restrict__ out) {
    int b = threadIdx.x;
    if (b < NB) {
        float acc = bout[0];
#pragma unroll 8
        for (int j = 0; j < 64; ++j) acc += qstar[b * 64 + j] * Wout[j];
        out[b] = acc;
    }
}

extern "C" void kernel_launch(void* const* d_in, const int* in_sizes, int n_in,
                              void* d_out, int out_size, void* d_ws, size_t ws_size,
                              hipStream_t stream) {
    const float* x     = (const float*)d_in[0];
    // d_in[1] adj unused; d_in[2] T == 8 (module constant)
    const float* ed    = (const float*)d_in[3];
    const int*   edges = (const int*)d_in[4];
    const int*   batch = (const int*)d_in[5];
    const float* Wi    = (const float*)d_in[6];
    const float* bi    = (const float*)d_in[7];
    const float* We1   = (const float*)d_in[8];
    const float* be1   = (const float*)d_in[9];
    const float* We2   = (const float*)d_in[10];
    const float* be2   = (const float*)d_in[11];
    const float* Wroot = (const float*)d_in[12];
    const float* bconv = (const float*)d_in[13];
    const float* gWih  = (const float*)d_in[14];
    const float* gWhh  = (const float*)d_in[15];
    const float* gbih  = (const float*)d_in[16];
    const float* gbhh  = (const float*)d_in[17];
    const float* lWih  = (const float*)d_in[18];
    const float* lWhh  = (const float*)d_in[19];
    const float* lbih  = (const float*)d_in[20];
    const float* lbhh  = (const float*)d_in[21];
    const float* Wout  = (const float*)d_in[22];
    const float* bout  = (const float*)d_in[23];
    float* out = (float*)d_out;

    const int* srcp = edges;
    const int* dstp = edges + NE;

    char* ws = (char*)d_ws;
    size_t off = 0;
    auto alloc = [&](size_t bytes) -> char* {
        char* p = ws + off;
        off += (bytes + 255) & ~(size_t)255;
        return p;
    };
    float* hA    = (float*)alloc((size_t)NN * D * 4);
    float* hB    = (float*)alloc((size_t)NN * D * 4);
    float* agg   = (float*)alloc((size_t)NN * D * 4);
    float* ebuf  = (float*)alloc((size_t)NN * 4);
    float* qstar = (float*)alloc((size_t)NB * 64 * 4);  // qstar,hl,cl contiguous
    float* hl    = (float*)alloc((size_t)NB * 32 * 4);
    float* cl    = (float*)alloc((size_t)NB * 32 * 4);
    int*   gst   = (int*)alloc((NB + 1) * 4);
    const size_t base = off;
    const size_t a_f32 = (size_t)NE * 1024 * 4;
    const size_t a_b16 = a_f32 / 2;
    // strict fit checks — tier 3 needs no big buffer at all
    const bool f32path  = (ws_size >= base + a_f32);
    const bool bf16path = (!f32path && ws_size >= base + a_b16);
    void* Abuf = nullptr;
    if (f32path)       Abuf = (void*)alloc(a_f32);
    else if (bf16path) Abuf = (void*)alloc(a_b16);

    hipLaunchKernelGGL(k_graph_start, dim3(1), dim3(128), 0, stream, batch, gst);
    hipLaunchKernelGGL(k_input_linear, dim3(NN * D / 256), dim3(256), 0, stream, x, Wi, bi, hA);
    if (f32path)
        hipLaunchKernelGGL((k_edge_net<float>), dim3(NE / 64, 8), dim3(256), 0, stream,
                           ed, We1, be1, We2, be2, (float*)Abuf);
    else if (bf16path)
        hipLaunchKernelGGL((k_edge_net<unsigned short>), dim3(NE / 64, 8), dim3(256), 0, stream,
                           ed, We1, be1, We2, be2, (unsigned short*)Abuf);
    hipMemsetAsync(qstar, 0, (size_t)(NB * 64 + NB * 32 + NB * 32) * 4, stream);

    float* hcur = hA;
    float* hnxt = hB;
    for (int t = 0; t < TST; ++t) {
        hipMemsetAsync(agg, 0, (size_t)NN * D * 4, stream);
        if (f32path)
            hipLaunchKernelGGL(k_msg_f32, dim3(NE / 32), dim3(256), 0, stream,
                               (const float*)Abuf, hcur, srcp, dstp, agg);
        else if (bf16path)
            hipLaunchKernelGGL(k_msg_bf16, dim3(NE / 64), dim3(256), 0, stream,
                               (const unsigned short*)Abuf, hcur, srcp, dstp, agg);
        else
            hipLaunchKernelGGL(k_msg_fused, dim3(NE / 64), dim3(256), 0, stream,
                               ed, We1, be1, We2, hcur, srcp, dstp, agg);
        hipLaunchKernelGGL(k_gru, dim3(NN * D / 256), dim3(256), 0, stream,
                           hcur, agg, Wroot, bconv, gWih, gWhh, gbih, gbhh, hnxt);
        float* tmp = hcur; hcur = hnxt; hnxt = tmp;
    }

    for (int s = 0; s < S2S; ++s)
        hipLaunchKernelGGL(k_s2s, dim3(NB), dim3(256), 0, stream,
                           hcur, gst, qstar, hl, cl, lWih, lWhh, lbih, lbhh, ebuf);

    hipLaunchKernelGGL(k_out, dim3(1), dim3(64), 0, stream, qstar, Wout, bout, out);
    (void)in_sizes; (void)n_in; (void)out_size;
}

// Round 3
// 6147.411 us; speedup vs baseline: 2.5382x; 2.5382x over previous
//
#include <hip/hip_runtime.h>
#include <hip/hip_bf16.h>

#define NN 20000   // nodes
#define NE 320000  // edges
#define NB 64      // graphs
#define DIN 16
#define DE 8
#define HE 128
#define D 32
#define TST 8
#define S2S 12

typedef __attribute__((ext_vector_type(8))) short short8x;   // 8 bf16 = 4 VGPRs (MFMA A/B frag)
typedef __attribute__((ext_vector_type(4))) float f32x4;     // MFMA C/D frag

__device__ __forceinline__ float sigf(float x) { return 1.f / (1.f + expf(-x)); }

__device__ __forceinline__ void split_bf16(float x, unsigned short& hi, unsigned short& lo) {
    __hip_bfloat16 h = __float2bfloat16(x);
    hi = *(unsigned short*)&h;
    float r = x - __bfloat162float(h);
    __hip_bfloat16 l = __float2bfloat16(r);
    lo = *(unsigned short*)&l;
}

// -------- graph segment starts: start[b] = lower_bound(batch, b), start[NB]=NN
__global__ void k_graph_start(const int* __restrict__ batch, int* __restrict__ start) {
    int b = threadIdx.x;
    if (b > NB) return;
    int lo = 0, hi = NN;
    while (lo < hi) {
        int mid = (lo + hi) >> 1;
        if (batch[mid] < b) lo = mid + 1; else hi = mid;
    }
    start[b] = lo;
}

// -------- Wt[k][f][d] = We2[k][d*32+f] (k<128), row 128 = be2; split hi/lo bf16
__global__ __launch_bounds__(256) void k_prep_w(
    const float* __restrict__ We2, const float* __restrict__ be2,
    unsigned short* __restrict__ wth, unsigned short* __restrict__ wtl) {
    int idx = blockIdx.x * 256 + threadIdx.x;  // = k*1024 + f*32 + d
    if (idx >= 129 * 1024) return;
    int k = idx >> 10, rem = idx & 1023, f = rem >> 5, d = rem & 31;
    float v = (k < 128) ? We2[k * 1024 + d * 32 + f] : be2[d * 32 + f];
    unsigned short hi, lo;
    split_bf16(v, hi, lo);
    wth[idx] = hi;
    wtl[idx] = lo;
}

// -------- h0 = x @ W_in + b_in  (+ optional bf16 hi/lo split emit)
__global__ __launch_bounds__(256) void k_input_linear(
    const float* __restrict__ x, const float* __restrict__ Win,
    const float* __restrict__ bin, float* __restrict__ h,
    unsigned short* __restrict__ hhi, unsigned short* __restrict__ hlo) {
    int idx = blockIdx.x * 256 + threadIdx.x;  // n*32+f, grid exact
    int n = idx >> 5, f = idx & 31;
    float acc = bin[f];
#pragma unroll
    for (int d = 0; d < DIN; ++d) acc += x[n * DIN + d] * Win[d * D + f];
    h[idx] = acc;
    if (hhi) {
        unsigned short hi, lo;
        split_bf16(acc, hi, lo);
        hhi[idx] = hi;
        hlo[idx] = lo;
    }
}

// -------- MFMA msg kernel: block = 64 edges, 4 waves x 16 edges each.
// msg[e,f] = sum_k z[e,k] * (H @ W_k)[e,f], computed transposed:
// T^T = W_k^T(16f x 32d) @ H^T(32d x 16e) via mfma_f32_16x16x32_bf16, hi/lo 3-pass.
__global__ __launch_bounds__(256) void k_msg_mfma(
    const float* __restrict__ ed, const float* __restrict__ We1,
    const float* __restrict__ be1,
    const unsigned short* __restrict__ wth, const unsigned short* __restrict__ wtl,
    const unsigned short* __restrict__ hhi, const unsigned short* __restrict__ hlo,
    const int* __restrict__ src, const int* __restrict__ dst,
    float* __restrict__ agg) {
    const int tid = threadIdx.x;
    const int e0 = blockIdx.x * 64;

    __shared__ float we1s[DE * HE];  // 4 KB
    __shared__ float be1s[HE];       // 0.5 KB
    __shared__ float eds[64][9];     // 2.3 KB
    __shared__ float zst[129][66];   // 34 KB  z[k][e_local], row 128 = 1.0 (be2 term)
    __shared__ int srcs[64];

    for (int i = tid; i < DE * HE; i += 256) we1s[i] = We1[i];
    if (tid < HE) be1s[tid] = be1[tid];
    if (tid < 64) srcs[tid] = src[e0 + tid];
    for (int i = tid; i < 64 * DE; i += 256) eds[i >> 3][i & 7] = ed[(size_t)e0 * DE + i];
    __syncthreads();

    {   // z phase: e = tid&63, kb = tid>>6 (32 k each)
        const int e = tid & 63, kb = tid >> 6;
        float edr[8];
#pragma unroll
        for (int j = 0; j < 8; ++j) edr[j] = eds[e][j];
        for (int m = 0; m < 32; ++m) {
            const int k = kb * 32 + m;
            float acc = be1s[k];
#pragma unroll
            for (int j = 0; j < 8; ++j) acc += edr[j] * we1s[j * HE + k];
            zst[k][e] = fmaxf(acc, 0.f);
        }
        if (tid < 64) zst[128][tid] = 1.f;  // virtual k for be2
    }
    __syncthreads();

    const int lane = tid & 63;
    const int wv = tid >> 6;                 // e-tile 0..3
    const int eloc = wv * 16 + (lane & 15);  // edge within block
    const int e = e0 + eloc;
    const int quad = lane >> 4;              // 0..3
    const int d0 = quad * 8;

    // B-frags (H^T): lane holds h[src[e]][d0..d0+8)  — persistent across k
    const size_t hb = (size_t)srcs[eloc] * 32 + d0;
    const short8x bhi = *(const short8x*)(hhi + hb);
    const short8x blo = *(const short8x*)(hlo + hb);

    // A-frag offsets within a k-row of Wt[k][f][d]
    const int b0 = (lane & 15) * 32 + d0;    // f-tile 0 (f=0..15)
    const int b1 = b0 + 16 * 32;             // f-tile 1 (f=16..31)

    short8x a0h = *(const short8x*)(wth + b0);
    short8x a1h = *(const short8x*)(wth + b1);
    short8x a0l = *(const short8x*)(wtl + b0);
    short8x a1l = *(const short8x*)(wtl + b1);

    f32x4 m0 = {0.f, 0.f, 0.f, 0.f}, m1 = {0.f, 0.f, 0.f, 0.f};

    for (int k = 0; k < 129; ++k) {
        const int kn = (k < 128) ? k + 1 : 128;  // prefetch next k (clamped)
        const unsigned short* ph = wth + kn * 1024;
        const unsigned short* pl = wtl + kn * 1024;
        const short8x n0h = *(const short8x*)(ph + b0);
        const short8x n1h = *(const short8x*)(ph + b1);
        const short8x n0l = *(const short8x*)(pl + b0);
        const short8x n1l = *(const short8x*)(pl + b1);

        f32x4 t0 = {0.f, 0.f, 0.f, 0.f}, t1 = {0.f, 0.f, 0.f, 0.f};
        t0 = __builtin_amdgcn_mfma_f32_16x16x32_bf16(a0h, bhi, t0, 0, 0, 0);
        t1 = __builtin_amdgcn_mfma_f32_16x16x32_bf16(a1h, bhi, t1, 0, 0, 0);
        t0 = __builtin_amdgcn_mfma_f32_16x16x32_bf16(a0l, bhi, t0, 0, 0, 0);
        t1 = __builtin_amdgcn_mfma_f32_16x16x32_bf16(a1l, bhi, t1, 0, 0, 0);
        t0 = __builtin_amdgcn_mfma_f32_16x16x32_bf16(a0h, blo, t0, 0, 0, 0);
        t1 = __builtin_amdgcn_mfma_f32_16x16x32_bf16(a1h, blo, t1, 0, 0, 0);

        const float zk = zst[k][eloc];
        m0 += zk * t0;
        m1 += zk * t1;

        a0h = n0h; a1h = n1h; a0l = n0l; a1l = n1l;
    }

    // epilogue: lane holds msg^T rows f = tile*16 + quad*4 + r, col = edge e
    const int dn = dst[e];
    float* ap = agg + (size_t)dn * 32 + quad * 4;
    atomicAdd(ap + 0, m0.x);
    atomicAdd(ap + 1, m0.y);
    atomicAdd(ap + 2, m0.z);
    atomicAdd(ap + 3, m0.w);
    atomicAdd(ap + 16 + 0, m1.x);
    atomicAdd(ap + 16 + 1, m1.y);
    atomicAdd(ap + 16 + 2, m1.z);
    atomicAdd(ap + 16 + 3, m1.w);
}

// -------- fallback (proven R2 path): recompute z per edge, fp32 VALU bilinear
__global__ __launch_bounds__(256) void k_msg_fused(
    const float* __restrict__ ed, const float* __restrict__ We1,
    const float* __restrict__ be1, const float* __restrict__ We2,
    const float* __restrict__ h, const int* __restrict__ src,
    const int* __restrict__ dst, float* __restrict__ agg) {
    const int tid = threadIdx.x;
    const int e0 = blockIdx.x * 64;
    __shared__ float we1s[DE * HE];
    __shared__ float be1s[HE];
    __shared__ float eds[64][9];
    __shared__ float zs[HE][64];
    __shared__ float hs[64][33];
    __shared__ float ws2s[4][1024];
    __shared__ int srcs[64];

    for (int i = tid; i < DE * HE; i += 256) we1s[i] = We1[i];
    if (tid < HE) be1s[tid] = be1[tid];
    if (tid < 64) srcs[tid] = src[e0 + tid];
    for (int i = tid; i < 64 * DE; i += 256) eds[i >> 3][i & 7] = ed[(size_t)e0 * DE + i];
    __syncthreads();

    {   // z phase
        const int e = tid & 63, kb = tid >> 6;
        float edr[8];
#pragma unroll
        for (int j = 0; j < 8; ++j) edr[j] = eds[e][j];
        for (int m = 0; m < 32; ++m) {
            const int k = kb * 32 + m;
            float acc = be1s[k];
#pragma unroll
            for (int j = 0; j < 8; ++j) acc += edr[j] * we1s[j * HE + k];
            zs[k][e] = fmaxf(acc, 0.f);
        }
    }
    for (int i = tid; i < 64 * 32; i += 256) {
        const int e = i >> 5, d = i & 31;
        hs[e][d] = h[(size_t)srcs[e] * D + d];
    }
    __syncthreads();

    const int ep = tid & 31, fg = tid >> 5;
    float hr[2][32];
#pragma unroll
    for (int d = 0; d < 32; ++d) {
        hr[0][d] = hs[ep * 2][d];
        hr[1][d] = hs[ep * 2 + 1][d];
    }
    float acc[2][4];
#pragma unroll
    for (int i = 0; i < 2; ++i)
#pragma unroll
        for (int j = 0; j < 4; ++j) acc[i][j] = 0.f;

    for (int kc = 0; kc < 32; ++kc) {
        __syncthreads();
#pragma unroll
        for (int r = 0; r < 4; ++r) {
            const int idx4 = tid + 256 * r;
            const int kr = idx4 >> 8, c4 = idx4 & 255;
            *(float4*)&ws2s[kr][c4 * 4] =
                *(const float4*)(We2 + (size_t)(kc * 4 + kr) * 1024 + c4 * 4);
        }
        __syncthreads();
#pragma unroll
        for (int kk = 0; kk < 4; ++kk) {
            const int k = kc * 4 + kk;
            const float z0 = zs[k][ep * 2], z1 = zs[k][ep * 2 + 1];
#pragma unroll
            for (int d = 0; d < 32; ++d) {
                const float4 w4 = *(const float4*)&ws2s[kk][d * 32 + fg * 4];
                const float c0 = z0 * hr[0][d], c1 = z1 * hr[1][d];
                acc[0][0] += c0 * w4.x; acc[0][1] += c0 * w4.y;
                acc[0][2] += c0 * w4.z; acc[0][3] += c0 * w4.w;
                acc[1][0] += c1 * w4.x; acc[1][1] += c1 * w4.y;
                acc[1][2] += c1 * w4.z; acc[1][3] += c1 * w4.w;
            }
        }
    }
#pragma unroll
    for (int i = 0; i < 2; ++i) {
        const int e = e0 + ep * 2 + i;
        float* ap = &agg[(size_t)dst[e] * D + fg * 4];
#pragma unroll
        for (int j = 0; j < 4; ++j) atomicAdd(ap + j, acc[i][j]);
    }
}

// -------- GRU cell per node (8 nodes x 32 f per block) (+ optional split emit)
__global__ __launch_bounds__(256) void k_gru(
    const float* __restrict__ h, const float* __restrict__ agg,
    const float* __restrict__ Wroot, const float* __restrict__ bconv,
    const float* __restrict__ Wih, const float* __restrict__ Whh,
    const float* __restrict__ bih, const float* __restrict__ bhh,
    float* __restrict__ hout,
    unsigned short* __restrict__ hhi, unsigned short* __restrict__ hlo) {
    const int idx = blockIdx.x * 256 + threadIdx.x;  // grid exact: NN*D/256
    const int n = idx >> 5, f = idx & 31, nl = threadIdx.x >> 5;
    __shared__ float hsh[8][33], msh[8][33];
    const float hv = h[n * D + f];
    hsh[nl][f] = hv;
    __syncthreads();
    float m = bconv[f] + agg[n * D + f];
#pragma unroll
    for (int d = 0; d < 32; ++d) m += hsh[nl][d] * Wroot[d * D + f];
    m = fmaxf(m, 0.f);
    msh[nl][f] = m;
    __syncthreads();
    float gir = bih[f], giz = bih[D + f], gin = bih[2 * D + f];
    float ghr = bhh[f], ghz = bhh[D + f], ghn = bhh[2 * D + f];
#pragma unroll
    for (int d = 0; d < 32; ++d) {
        const float md = msh[nl][d], hd = hsh[nl][d];
        gir += md * Wih[f * D + d];
        giz += md * Wih[(D + f) * D + d];
        gin += md * Wih[(2 * D + f) * D + d];
        ghr += hd * Whh[f * D + d];
        ghz += hd * Whh[(D + f) * D + d];
        ghn += hd * Whh[(2 * D + f) * D + d];
    }
    const float r = sigf(gir + ghr);
    const float z = sigf(giz + ghz);
    const float nn2 = tanhf(gin + r * ghn);
    const float ho = (1.f - z) * nn2 + z * hv;
    hout[n * D + f] = ho;
    if (hhi) {
        unsigned short hi, lo;
        split_bf16(ho, hi, lo);
        hhi[idx] = hi;
        hlo[idx] = lo;
    }
}

// -------- one Set2Set step: LSTM cell + segment softmax attention, block = graph
__global__ __launch_bounds__(256) void k_s2s(
    const float* __restrict__ h, const int* __restrict__ start,
    float* __restrict__ qstar, float* __restrict__ hl, float* __restrict__ cl,
    const float* __restrict__ Wih, const float* __restrict__ Whh,
    const float* __restrict__ bih, const float* __restrict__ bhh,
    float* __restrict__ ebuf) {
    const int b = blockIdx.x, t = threadIdx.x;
    __shared__ float qst[64], hls[32], gates[128], qs[32];
    __shared__ float red[256];
    __shared__ float rsum[8][33];
    if (t < 64) qst[t] = qstar[b * 64 + t];
    if (t < 32) hls[t] = hl[b * 32 + t];
    __syncthreads();
    if (t < 128) {
        float g = bih[t] + bhh[t];
#pragma unroll 8
        for (int j = 0; j < 64; ++j) g += qst[j] * Wih[t * 64 + j];
#pragma unroll 8
        for (int j = 0; j < 32; ++j) g += hls[j] * Whh[t * 32 + j];
        gates[t] = g;
    }
    __syncthreads();
    if (t < 32) {  // i,f,g,o order
        const float ig = sigf(gates[t]);
        const float fg = sigf(gates[32 + t]);
        const float gg = tanhf(gates[64 + t]);
        const float og = sigf(gates[96 + t]);
        const float c = fg * cl[b * 32 + t] + ig * gg;
        const float q = og * tanhf(c);
        cl[b * 32 + t] = c;
        hl[b * 32 + t] = q;
        qstar[b * 64 + t] = q;
        qs[t] = q;
    }
    __syncthreads();
    const int s0 = start[b], s1 = start[b + 1];
    float lmax = -3.4e38f;
    for (int n = s0 + t; n < s1; n += 256) {
        const float4* hv = (const float4*)(h + (size_t)n * D);
        float e = 0.f;
#pragma unroll
        for (int u = 0; u < 8; ++u) {
            const float4 v = hv[u];
            e += v.x * qs[u * 4] + v.y * qs[u * 4 + 1] + v.z * qs[u * 4 + 2] + v.w * qs[u * 4 + 3];
        }
        ebuf[n] = e;
        lmax = fmaxf(lmax, e);
    }
    red[t] = lmax;
    __syncthreads();
    for (int s = 128; s > 0; s >>= 1) {
        if (t < s) red[t] = fmaxf(red[t], red[t + s]);
        __syncthreads();
    }
    const float smax = red[0];
    __syncthreads();
    float lsum = 0.f;
    for (int n = s0 + t; n < s1; n += 256) {
        const float w = expf(ebuf[n] - smax);
        ebuf[n] = w;
        lsum += w;
    }
    red[t] = lsum;
    __syncthreads();
    for (int s = 128; s > 0; s >>= 1) {
        if (t < s) red[t] += red[t + s];
        __syncthreads();
    }
    const float den = red[0];
    const float inv = (den > 0.f) ? 1.f / den : 0.f;
    const int fl = t & 31, sl = t >> 5;
    float racc = 0.f;
    for (int n = s0 + sl; n < s1; n += 8) racc += ebuf[n] * h[(size_t)n * D + fl];
    rsum[sl][fl] = racc;
    __syncthreads();
    if (sl == 0) {
        float rv = 0.f;
#pragma unroll
        for (int u = 0; u < 8; ++u) rv += rsum[u][fl];
        qstar[b * 64 + 32 + fl] = rv * inv;
    }
}

// -------- out = q_star @ W_out + b_out
__global__ void k_out(const float* __restrict__ qstar, const float* __restrict__ Wout,
                      const float* __restrict__ bout, float* __restrict__ out) {
    int b = threadIdx.x;
    if (b < NB) {
        float acc = bout[0];
#pragma unroll 8
        for (int j = 0; j < 64; ++j) acc += qstar[b * 64 + j] * Wout[j];
        out[b] = acc;
    }
}

extern "C" void kernel_launch(void* const* d_in, const int* in_sizes, int n_in,
                              void* d_out, int out_size, void* d_ws, size_t ws_size,
                              hipStream_t stream) {
    const float* x     = (const float*)d_in[0];
    // d_in[1] adj unused; d_in[2] T == 8 (module constant)
    const float* ed    = (const float*)d_in[3];
    const int*   edges = (const int*)d_in[4];
    const int*   batch = (const int*)d_in[5];
    const float* Wi    = (const float*)d_in[6];
    const float* bi    = (const float*)d_in[7];
    const float* We1   = (const float*)d_in[8];
    const float* be1   = (const float*)d_in[9];
    const float* We2   = (const float*)d_in[10];
    const float* be2   = (const float*)d_in[11];
    const float* Wroot = (const float*)d_in[12];
    const float* bconv = (const float*)d_in[13];
    const float* gWih  = (const float*)d_in[14];
    const float* gWhh  = (const float*)d_in[15];
    const float* gbih  = (const float*)d_in[16];
    const float* gbhh  = (const float*)d_in[17];
    const float* lWih  = (const float*)d_in[18];
    const float* lWhh  = (const float*)d_in[19];
    const float* lbih  = (const float*)d_in[20];
    const float* lbhh  = (const float*)d_in[21];
    const float* Wout  = (const float*)d_in[22];
    const float* bout  = (const float*)d_in[23];
    float* out = (float*)d_out;

    const int* srcp = edges;
    const int* dstp = edges + NE;

    char* ws = (char*)d_ws;
    size_t off = 0;
    auto alloc = [&](size_t bytes) -> char* {
        char* p = ws + off;
        off += (bytes + 255) & ~(size_t)255;
        return p;
    };
    float* hA    = (float*)alloc((size_t)NN * D * 4);
    float* hB    = (float*)alloc((size_t)NN * D * 4);
    float* agg   = (float*)alloc((size_t)NN * D * 4);
    float* ebuf  = (float*)alloc((size_t)NN * 4);
    float* qstar = (float*)alloc((size_t)NB * 64 * 4);  // qstar,hl,cl contiguous
    float* hl    = (float*)alloc((size_t)NB * 32 * 4);
    float* cl    = (float*)alloc((size_t)NB * 32 * 4);
    int*   gst   = (int*)alloc((NB + 1) * 4);
    // MFMA-path extras (~5.6 MB): double-buffered h hi/lo splits + transposed We2 hi/lo
    unsigned short* hhiA = (unsigned short*)alloc((size_t)NN * D * 2);
    unsigned short* hloA = (unsigned short*)alloc((size_t)NN * D * 2);
    unsigned short* hhiB = (unsigned short*)alloc((size_t)NN * D * 2);
    unsigned short* hloB = (unsigned short*)alloc((size_t)NN * D * 2);
    unsigned short* wth  = (unsigned short*)alloc((size_t)129 * 1024 * 2);
    unsigned short* wtl  = (unsigned short*)alloc((size_t)129 * 1024 * 2);
    const bool mfma_path = (ws_size >= off);

    hipLaunchKernelGGL(k_graph_start, dim3(1), dim3(128), 0, stream, batch, gst);
    hipLaunchKernelGGL(k_input_linear, dim3(NN * D / 256), dim3(256), 0, stream, x, Wi, bi, hA,
                       mfma_path ? hhiA : (unsigned short*)nullptr,
                       mfma_path ? hloA : (unsigned short*)nullptr);
    if (mfma_path)
        hipLaunchKernelGGL(k_prep_w, dim3((129 * 1024 + 255) / 256), dim3(256), 0, stream,
                           We2, be2, wth, wtl);
    hipMemsetAsync(qstar, 0, (size_t)(NB * 64 + NB * 32 + NB * 32) * 4, stream);

    float* hcur = hA;
    float* hnxt = hB;
    unsigned short *hhic = hhiA, *hloc = hloA, *hhin = hhiB, *hlon = hhiB ? hloB : nullptr;
    for (int t = 0; t < TST; ++t) {
        hipMemsetAsync(agg, 0, (size_t)NN * D * 4, stream);
        if (mfma_path)
            hipLaunchKernelGGL(k_msg_mfma, dim3(NE / 64), dim3(256), 0, stream,
                               ed, We1, be1, wth, wtl, hhic, hloc, srcp, dstp, agg);
        else
            hipLaunchKernelGGL(k_msg_fused, dim3(NE / 64), dim3(256), 0, stream,
                               ed, We1, be1, We2, hcur, srcp, dstp, agg);
        hipLaunchKernelGGL(k_gru, dim3(NN * D / 256), dim3(256), 0, stream,
                           hcur, agg, Wroot, bconv, gWih, gWhh, gbih, gbhh, hnxt,
                           mfma_path ? hhin : (unsigned short*)nullptr,
                           mfma_path ? hlon : (unsigned short*)nullptr);
        float* tf = hcur; hcur = hnxt; hnxt = tf;
        unsigned short* ts;
        ts = hhic; hhic = hhin; hhin = ts;
        ts = hloc; hloc = hlon; hlon = ts;
    }

    for (int s = 0; s < S2S; ++s)
        hipLaunchKernelGGL(k_s2s, dim3(NB), dim3(256), 0, stream,
                           hcur, gst, qstar, hl, cl, lWih, lWhh, lbih, lbhh, ebuf);

    hipLaunchKernelGGL(k_out, dim3(1), dim3(64), 0, stream, qstar, Wout, bout, out);
    (void)in_sizes; (void)n_in; (void)out_size;
}

// Round 4
// 5558.015 us; speedup vs baseline: 2.8073x; 1.1060x over previous
//
#include <hip/hip_runtime.h>
#include <hip/hip_bf16.h>

#define NN 20000   // nodes
#define NE 320000  // edges
#define NB 64      // graphs
#define DIN 16
#define DE 8
#define HE 128
#define D 32
#define TST 8
#define S2S 12

typedef __attribute__((ext_vector_type(8))) short short8x;   // 8 bf16 = 4 VGPRs (MFMA A/B frag)
typedef __attribute__((ext_vector_type(4))) float f32x4;     // MFMA C/D frag

__device__ __forceinline__ float sigf(float x) { return 1.f / (1.f + expf(-x)); }

__device__ __forceinline__ void split_bf16(float x, unsigned short& hi, unsigned short& lo) {
    __hip_bfloat16 h = __float2bfloat16(x);
    hi = *(unsigned short*)&h;
    float r = x - __bfloat162float(h);
    __hip_bfloat16 l = __float2bfloat16(r);
    lo = *(unsigned short*)&l;
}

// -------- graph segment starts: start[b] = lower_bound(batch, b), start[NB]=NN
__global__ void k_graph_start(const int* __restrict__ batch, int* __restrict__ start) {
    int b = threadIdx.x;
    if (b > NB) return;
    int lo = 0, hi = NN;
    while (lo < hi) {
        int mid = (lo + hi) >> 1;
        if (batch[mid] < b) lo = mid + 1; else hi = mid;
    }
    start[b] = lo;
}

// -------- Wt[k][f][d] = We2[k][d*32+f] (k<128), row 128 = be2; split hi/lo bf16
__global__ __launch_bounds__(256) void k_prep_w(
    const float* __restrict__ We2, const float* __restrict__ be2,
    unsigned short* __restrict__ wth, unsigned short* __restrict__ wtl) {
    int idx = blockIdx.x * 256 + threadIdx.x;  // = k*1024 + f*32 + d
    if (idx >= 129 * 1024) return;
    int k = idx >> 10, rem = idx & 1023, f = rem >> 5, d = rem & 31;
    float v = (k < 128) ? We2[k * 1024 + d * 32 + f] : be2[d * 32 + f];
    unsigned short hi, lo;
    split_bf16(v, hi, lo);
    wth[idx] = hi;
    wtl[idx] = lo;
}

// -------- h0 = x @ W_in + b_in  (+ optional bf16 hi/lo split emit)
__global__ __launch_bounds__(256) void k_input_linear(
    const float* __restrict__ x, const float* __restrict__ Win,
    const float* __restrict__ bin, float* __restrict__ h,
    unsigned short* __restrict__ hhi, unsigned short* __restrict__ hlo) {
    int idx = blockIdx.x * 256 + threadIdx.x;  // n*32+f, grid exact
    int n = idx >> 5, f = idx & 31;
    float acc = bin[f];
#pragma unroll
    for (int d = 0; d < DIN; ++d) acc += x[n * DIN + d] * Win[d * D + f];
    h[idx] = acc;
    if (hhi) {
        unsigned short hi, lo;
        split_bf16(acc, hi, lo);
        hhi[idx] = hi;
        hlo[idx] = lo;
    }
}

// -------- MFMA msg kernel v2: block = 64 edges, 4 waves x 16 edges.
// z in registers (32/lane) + __shfl broadcast; W-frags in a 4-slot register
// ring with distance-3 prefetch. LDS only We1/be1 (~4.6 KB).
#define LDFRAG(slot, kk)                                          \
    do {                                                          \
        const unsigned short* _ph = wth + ((size_t)(kk) << 10);   \
        const unsigned short* _pl = wtl + ((size_t)(kk) << 10);   \
        ring[slot][0] = *(const short8x*)(_ph + b0);              \
        ring[slot][1] = *(const short8x*)(_ph + b1);              \
        ring[slot][2] = *(const short8x*)(_pl + b0);              \
        ring[slot][3] = *(const short8x*)(_pl + b1);              \
    } while (0)

__global__ __launch_bounds__(256) void k_msg_mfma(
    const float* __restrict__ ed, const float* __restrict__ We1,
    const float* __restrict__ be1,
    const unsigned short* __restrict__ wth, const unsigned short* __restrict__ wtl,
    const unsigned short* __restrict__ hhi, const unsigned short* __restrict__ hlo,
    const int* __restrict__ src, const int* __restrict__ dst,
    float* __restrict__ agg) {
    const int tid = threadIdx.x;
    const int e0 = blockIdx.x * 64;

    __shared__ float we1s[DE * HE];  // 4 KB, [j][k]
    __shared__ float be1s[HE];       // 0.5 KB

    for (int i = tid; i < DE * HE; i += 256) we1s[i] = We1[i];
    if (tid < HE) be1s[tid] = be1[tid];

    const int lane = tid & 63;
    const int wv = tid >> 6;
    const int eidx = lane & 15;
    const int quad = lane >> 4;
    const int eloc = wv * 16 + eidx;
    const int e = e0 + eloc;
    const int d0 = quad * 8;

    const int sn = src[e];
    const int dn = dst[e];

    // A-frag element offsets within a k-row of Wt[k][f][d]
    const int b0 = eidx * 32 + d0;   // f-tile 0 (f=0..15)
    const int b1 = b0 + 16 * 32;     // f-tile 1 (f=16..31)

    // issue long-latency loads early: B-frags, ed row, ring priming
    const size_t hb = (size_t)sn * 32 + d0;
    const short8x bhi = *(const short8x*)(hhi + hb);
    const short8x blo = *(const short8x*)(hlo + hb);
    const float4 edv0 = *(const float4*)(ed + (size_t)e * 8);
    const float4 edv1 = *(const float4*)(ed + (size_t)e * 8 + 4);

    short8x ring[4][4];
    LDFRAG(0, 0);
    LDFRAG(1, 1);
    LDFRAG(2, 2);

    __syncthreads();  // we1s/be1s ready

    // z-compute: lane covers k in [quad*32, quad*32+32) for its edge
    float edr[8];
    edr[0] = edv0.x; edr[1] = edv0.y; edr[2] = edv0.z; edr[3] = edv0.w;
    edr[4] = edv1.x; edr[5] = edv1.y; edr[6] = edv1.z; edr[7] = edv1.w;
    float zreg[32];
#pragma unroll
    for (int m = 0; m < 32; ++m) {
        const int kk = (quad << 5) + m;
        float acc = be1s[kk];
#pragma unroll
        for (int j = 0; j < 8; ++j) acc += edr[j] * we1s[j * 128 + kk];
        zreg[m] = fmaxf(acc, 0.f);
    }

    f32x4 m0 = {0.f, 0.f, 0.f, 0.f}, m1 = {0.f, 0.f, 0.f, 0.f};

    for (int q = 0; q < 4; ++q) {
        const int bsrc = q * 16 + eidx;  // shfl source lane for this k-chunk
#pragma unroll
        for (int m = 0; m < 32; ++m) {
            const int k = q * 32 + m;
            const int slot = m & 3;           // == k & 3
            const int pslot = (m + 3) & 3;    // == (k+3) & 3
            int kn = k + 3;
            kn = (kn > 128) ? 128 : kn;
            LDFRAG(pslot, kn);

            const float zk = __shfl(zreg[m], bsrc);

            f32x4 t0 = {0.f, 0.f, 0.f, 0.f}, t1 = {0.f, 0.f, 0.f, 0.f};
            t0 = __builtin_amdgcn_mfma_f32_16x16x32_bf16(ring[slot][0], bhi, t0, 0, 0, 0);
            t1 = __builtin_amdgcn_mfma_f32_16x16x32_bf16(ring[slot][1], bhi, t1, 0, 0, 0);
            t0 = __builtin_amdgcn_mfma_f32_16x16x32_bf16(ring[slot][2], bhi, t0, 0, 0, 0);
            t1 = __builtin_amdgcn_mfma_f32_16x16x32_bf16(ring[slot][3], bhi, t1, 0, 0, 0);
            t0 = __builtin_amdgcn_mfma_f32_16x16x32_bf16(ring[slot][0], blo, t0, 0, 0, 0);
            t1 = __builtin_amdgcn_mfma_f32_16x16x32_bf16(ring[slot][1], blo, t1, 0, 0, 0);

            m0 += zk * t0;
            m1 += zk * t1;
        }
    }
    {   // virtual k=128 (be2 row, z == 1), frags sit in slot 0
        f32x4 t0 = {0.f, 0.f, 0.f, 0.f}, t1 = {0.f, 0.f, 0.f, 0.f};
        t0 = __builtin_amdgcn_mfma_f32_16x16x32_bf16(ring[0][0], bhi, t0, 0, 0, 0);
        t1 = __builtin_amdgcn_mfma_f32_16x16x32_bf16(ring[0][1], bhi, t1, 0, 0, 0);
        t0 = __builtin_amdgcn_mfma_f32_16x16x32_bf16(ring[0][2], bhi, t0, 0, 0, 0);
        t1 = __builtin_amdgcn_mfma_f32_16x16x32_bf16(ring[0][3], bhi, t1, 0, 0, 0);
        t0 = __builtin_amdgcn_mfma_f32_16x16x32_bf16(ring[0][0], blo, t0, 0, 0, 0);
        t1 = __builtin_amdgcn_mfma_f32_16x16x32_bf16(ring[0][1], blo, t1, 0, 0, 0);
        m0 += t0;
        m1 += t1;
    }

    // epilogue: lane holds msg^T rows f = tile*16 + quad*4 + r, col = edge e
    float* ap = agg + (size_t)dn * 32 + quad * 4;
    atomicAdd(ap + 0, m0.x);
    atomicAdd(ap + 1, m0.y);
    atomicAdd(ap + 2, m0.z);
    atomicAdd(ap + 3, m0.w);
    atomicAdd(ap + 16 + 0, m1.x);
    atomicAdd(ap + 16 + 1, m1.y);
    atomicAdd(ap + 16 + 2, m1.z);
    atomicAdd(ap + 16 + 3, m1.w);
}

// -------- fallback (proven R2 path): recompute z per edge, fp32 VALU bilinear
__global__ __launch_bounds__(256) void k_msg_fused(
    const float* __restrict__ ed, const float* __restrict__ We1,
    const float* __restrict__ be1, const float* __restrict__ We2,
    const float* __restrict__ h, const int* __restrict__ src,
    const int* __restrict__ dst, float* __restrict__ agg) {
    const int tid = threadIdx.x;
    const int e0 = blockIdx.x * 64;
    __shared__ float we1s[DE * HE];
    __shared__ float be1s[HE];
    __shared__ float eds[64][9];
    __shared__ float zs[HE][64];
    __shared__ float hs[64][33];
    __shared__ float ws2s[4][1024];
    __shared__ int srcs[64];

    for (int i = tid; i < DE * HE; i += 256) we1s[i] = We1[i];
    if (tid < HE) be1s[tid] = be1[tid];
    if (tid < 64) srcs[tid] = src[e0 + tid];
    for (int i = tid; i < 64 * DE; i += 256) eds[i >> 3][i & 7] = ed[(size_t)e0 * DE + i];
    __syncthreads();

    {   // z phase
        const int e = tid & 63, kb = tid >> 6;
        float edr[8];
#pragma unroll
        for (int j = 0; j < 8; ++j) edr[j] = eds[e][j];
        for (int m = 0; m < 32; ++m) {
            const int k = kb * 32 + m;
            float acc = be1s[k];
#pragma unroll
            for (int j = 0; j < 8; ++j) acc += edr[j] * we1s[j * HE + k];
            zs[k][e] = fmaxf(acc, 0.f);
        }
    }
    for (int i = tid; i < 64 * 32; i += 256) {
        const int e = i >> 5, d = i & 31;
        hs[e][d] = h[(size_t)srcs[e] * D + d];
    }
    __syncthreads();

    const int ep = tid & 31, fg = tid >> 5;
    float hr[2][32];
#pragma unroll
    for (int d = 0; d < 32; ++d) {
        hr[0][d] = hs[ep * 2][d];
        hr[1][d] = hs[ep * 2 + 1][d];
    }
    float acc[2][4];
#pragma unroll
    for (int i = 0; i < 2; ++i)
#pragma unroll
        for (int j = 0; j < 4; ++j) acc[i][j] = 0.f;

    for (int kc = 0; kc < 32; ++kc) {
        __syncthreads();
#pragma unroll
        for (int r = 0; r < 4; ++r) {
            const int idx4 = tid + 256 * r;
            const int kr = idx4 >> 8, c4 = idx4 & 255;
            *(float4*)&ws2s[kr][c4 * 4] =
                *(const float4*)(We2 + (size_t)(kc * 4 + kr) * 1024 + c4 * 4);
        }
        __syncthreads();
#pragma unroll
        for (int kk = 0; kk < 4; ++kk) {
            const int k = kc * 4 + kk;
            const float z0 = zs[k][ep * 2], z1 = zs[k][ep * 2 + 1];
#pragma unroll
            for (int d = 0; d < 32; ++d) {
                const float4 w4 = *(const float4*)&ws2s[kk][d * 32 + fg * 4];
                const float c0 = z0 * hr[0][d], c1 = z1 * hr[1][d];
                acc[0][0] += c0 * w4.x; acc[0][1] += c0 * w4.y;
                acc[0][2] += c0 * w4.z; acc[0][3] += c0 * w4.w;
                acc[1][0] += c1 * w4.x; acc[1][1] += c1 * w4.y;
                acc[1][2] += c1 * w4.z; acc[1][3] += c1 * w4.w;
            }
        }
    }
#pragma unroll
    for (int i = 0; i < 2; ++i) {
        const int e = e0 + ep * 2 + i;
        float* ap = &agg[(size_t)dst[e] * D + fg * 4];
#pragma unroll
        for (int j = 0; j < 4; ++j) atomicAdd(ap + j, acc[i][j]);
    }
}

// -------- GRU cell per node (8 nodes x 32 f per block) (+ optional split emit)
__global__ __launch_bounds__(256) void k_gru(
    const float* __restrict__ h, const float* __restrict__ agg,
    const float* __restrict__ Wroot, const float* __restrict__ bconv,
    const float* __restrict__ Wih, const float* __restrict__ Whh,
    const float* __restrict__ bih, const float* __restrict__ bhh,
    float* __restrict__ hout,
    unsigned short* __restrict__ hhi, unsigned short* __restrict__ hlo) {
    const int idx = blockIdx.x * 256 + threadIdx.x;  // grid exact: NN*D/256
    const int n = idx >> 5, f = idx & 31, nl = threadIdx.x >> 5;
    __shared__ float hsh[8][33], msh[8][33];
    const float hv = h[n * D + f];
    hsh[nl][f] = hv;
    __syncthreads();
    float m = bconv[f] + agg[n * D + f];
#pragma unroll
    for (int d = 0; d < 32; ++d) m += hsh[nl][d] * Wroot[d * D + f];
    m = fmaxf(m, 0.f);
    msh[nl][f] = m;
    __syncthreads();
    float gir = bih[f], giz = bih[D + f], gin = bih[2 * D + f];
    float ghr = bhh[f], ghz = bhh[D + f], ghn = bhh[2 * D + f];
#pragma unroll
    for (int d = 0; d < 32; ++d) {
        const float md = msh[nl][d], hd = hsh[nl][d];
        gir += md * Wih[f * D + d];
        giz += md * Wih[(D + f) * D + d];
        gin += md * Wih[(2 * D + f) * D + d];
        ghr += hd * Whh[f * D + d];
        ghz += hd * Whh[(D + f) * D + d];
        ghn += hd * Whh[(2 * D + f) * D + d];
    }
    const float r = sigf(gir + ghr);
    const float z = sigf(giz + ghz);
    const float nn2 = tanhf(gin + r * ghn);
    const float ho = (1.f - z) * nn2 + z * hv;
    hout[n * D + f] = ho;
    if (hhi) {
        unsigned short hi, lo;
        split_bf16(ho, hi, lo);
        hhi[idx] = hi;
        hlo[idx] = lo;
    }
}

// -------- one Set2Set step: LSTM cell + segment softmax attention, block = graph
__global__ __launch_bounds__(256) void k_s2s(
    const float* __restrict__ h, const int* __restrict__ start,
    float* __restrict__ qstar, float* __restrict__ hl, float* __restrict__ cl,
    const float* __restrict__ Wih, const float* __restrict__ Whh,
    const float* __restrict__ bih, const float* __restrict__ bhh,
    float* __restrict__ ebuf) {
    const int b = blockIdx.x, t = threadIdx.x;
    __shared__ float qst[64], hls[32], gates[128], qs[32];
    __shared__ float red[256];
    __shared__ float rsum[8][33];
    if (t < 64) qst[t] = qstar[b * 64 + t];
    if (t < 32) hls[t] = hl[b * 32 + t];
    __syncthreads();
    if (t < 128) {
        float g = bih[t] + bhh[t];
#pragma unroll 8
        for (int j = 0; j < 64; ++j) g += qst[j] * Wih[t * 64 + j];
#pragma unroll 8
        for (int j = 0; j < 32; ++j) g += hls[j] * Whh[t * 32 + j];
        gates[t] = g;
    }
    __syncthreads();
    if (t < 32) {  // i,f,g,o order
        const float ig = sigf(gates[t]);
        const float fg = sigf(gates[32 + t]);
        const float gg = tanhf(gates[64 + t]);
        const float og = sigf(gates[96 + t]);
        const float c = fg * cl[b * 32 + t] + ig * gg;
        const float q = og * tanhf(c);
        cl[b * 32 + t] = c;
        hl[b * 32 + t] = q;
        qstar[b * 64 + t] = q;
        qs[t] = q;
    }
    __syncthreads();
    const int s0 = start[b], s1 = start[b + 1];
    float lmax = -3.4e38f;
    for (int n = s0 + t; n < s1; n += 256) {
        const float4* hv = (const float4*)(h + (size_t)n * D);
        float e = 0.f;
#pragma unroll
        for (int u = 0; u < 8; ++u) {
            const float4 v = hv[u];
            e += v.x * qs[u * 4] + v.y * qs[u * 4 + 1] + v.z * qs[u * 4 + 2] + v.w * qs[u * 4 + 3];
        }
        ebuf[n] = e;
        lmax = fmaxf(lmax, e);
    }
    red[t] = lmax;
    __syncthreads();
    for (int s = 128; s > 0; s >>= 1) {
        if (t < s) red[t] = fmaxf(red[t], red[t + s]);
        __syncthreads();
    }
    const float smax = red[0];
    __syncthreads();
    float lsum = 0.f;
    for (int n = s0 + t; n < s1; n += 256) {
        const float w = expf(ebuf[n] - smax);
        ebuf[n] = w;
        lsum += w;
    }
    red[t] = lsum;
    __syncthreads();
    for (int s = 128; s > 0; s >>= 1) {
        if (t < s) red[t] += red[t + s];
        __syncthreads();
    }
    const float den = red[0];
    const float inv = (den > 0.f) ? 1.f / den : 0.f;
    const int fl = t & 31, sl = t >> 5;
    float racc = 0.f;
    for (int n = s0 + sl; n < s1; n += 8) racc += ebuf[n] * h[(size_t)n * D + fl];
    rsum[sl][fl] = racc;
    __syncthreads();
    if (sl == 0) {
        float rv = 0.f;
#pragma unroll
        for (int u = 0; u < 8; ++u) rv += rsum[u][fl];
        qstar[b * 64 + 32 + fl] = rv * inv;
    }
}

// -------- out = q_star @ W_out + b_out
__global__ void k_out(const float* __restrict__ qstar, const float* __restrict__ Wout,
                      const float* __restrict__ bout, float* __restrict__ out) {
    int b = threadIdx.x;
    if (b < NB) {
        float acc = bout[0];
#pragma unroll 8
        for (int j = 0; j < 64; ++j) acc += qstar[b * 64 + j] * Wout[j];
        out[b] = acc;
    }
}

extern "C" void kernel_launch(void* const* d_in, const int* in_sizes, int n_in,
                              void* d_out, int out_size, void* d_ws, size_t ws_size,
                              hipStream_t stream) {
    const float* x     = (const float*)d_in[0];
    // d_in[1] adj unused; d_in[2] T == 8 (module constant)
    const float* ed    = (const float*)d_in[3];
    const int*   edges = (const int*)d_in[4];
    const int*   batch = (const int*)d_in[5];
    const float* Wi    = (const float*)d_in[6];
    const float* bi    = (const float*)d_in[7];
    const float* We1   = (const float*)d_in[8];
    const float* be1   = (const float*)d_in[9];
    const float* We2   = (const float*)d_in[10];
    const float* be2   = (const float*)d_in[11];
    const float* Wroot = (const float*)d_in[12];
    const float* bconv = (const float*)d_in[13];
    const float* gWih  = (const float*)d_in[14];
    const float* gWhh  = (const float*)d_in[15];
    const float* gbih  = (const float*)d_in[16];
    const float* gbhh  = (const float*)d_in[17];
    const float* lWih  = (const float*)d_in[18];
    const float* lWhh  = (const float*)d_in[19];
    const float* lbih  = (const float*)d_in[20];
    const float* lbhh  = (const float*)d_in[21];
    const float* Wout  = (const float*)d_in[22];
    const float* bout  = (const float*)d_in[23];
    float* out = (float*)d_out;

    const int* srcp = edges;
    const int* dstp = edges + NE;

    char* ws = (char*)d_ws;
    size_t off = 0;
    auto alloc = [&](size_t bytes) -> char* {
        char* p = ws + off;
        off += (bytes + 255) & ~(size_t)255;
        return p;
    };
    float* hA    = (float*)alloc((size_t)NN * D * 4);
    float* hB    = (float*)alloc((size_t)NN * D * 4);
    float* agg   = (float*)alloc((size_t)NN * D * 4);
    float* ebuf  = (float*)alloc((size_t)NN * 4);
    float* qstar = (float*)alloc((size_t)NB * 64 * 4);  // qstar,hl,cl contiguous
    float* hl    = (float*)alloc((size_t)NB * 32 * 4);
    float* cl    = (float*)alloc((size_t)NB * 32 * 4);
    int*   gst   = (int*)alloc((NB + 1) * 4);
    // MFMA-path extras (~5.6 MB): double-buffered h hi/lo splits + transposed We2 hi/lo
    unsigned short* hhiA = (unsigned short*)alloc((size_t)NN * D * 2);
    unsigned short* hloA = (unsigned short*)alloc((size_t)NN * D * 2);
    unsigned short* hhiB = (unsigned short*)alloc((size_t)NN * D * 2);
    unsigned short* hloB = (unsigned short*)alloc((size_t)NN * D * 2);
    unsigned short* wth  = (unsigned short*)alloc((size_t)129 * 1024 * 2);
    unsigned short* wtl  = (unsigned short*)alloc((size_t)129 * 1024 * 2);
    const bool mfma_path = (ws_size >= off);

    hipLaunchKernelGGL(k_graph_start, dim3(1), dim3(128), 0, stream, batch, gst);
    hipLaunchKernelGGL(k_input_linear, dim3(NN * D / 256), dim3(256), 0, stream, x, Wi, bi, hA,
                       mfma_path ? hhiA : (unsigned short*)nullptr,
                       mfma_path ? hloA : (unsigned short*)nullptr);
    if (mfma_path)
        hipLaunchKernelGGL(k_prep_w, dim3((129 * 1024 + 255) / 256), dim3(256), 0, stream,
                           We2, be2, wth, wtl);
    hipMemsetAsync(qstar, 0, (size_t)(NB * 64 + NB * 32 + NB * 32) * 4, stream);

    float* hcur = hA;
    float* hnxt = hB;
    unsigned short *hhic = hhiA, *hloc = hloA, *hhin = hhiB, *hlon = hloB;
    for (int t = 0; t < TST; ++t) {
        hipMemsetAsync(agg, 0, (size_t)NN * D * 4, stream);
        if (mfma_path)
            hipLaunchKernelGGL(k_msg_mfma, dim3(NE / 64), dim3(256), 0, stream,
                               ed, We1, be1, wth, wtl, hhic, hloc, srcp, dstp, agg);
        else
            hipLaunchKernelGGL(k_msg_fused, dim3(NE / 64), dim3(256), 0, stream,
                               ed, We1, be1, We2, hcur, srcp, dstp, agg);
        hipLaunchKernelGGL(k_gru, dim3(NN * D / 256), dim3(256), 0, stream,
                           hcur, agg, Wroot, bconv, gWih, gWhh, gbih, gbhh, hnxt,
                           mfma_path ? hhin : (unsigned short*)nullptr,
                           mfma_path ? hlon : (unsigned short*)nullptr);
        float* tf = hcur; hcur = hnxt; hnxt = tf;
        unsigned short* ts;
        ts = hhic; hhic = hhin; hhin = ts;
        ts = hloc; hloc = hlon; hlon = ts;
    }

    for (int s = 0; s < S2S; ++s)
        hipLaunchKernelGGL(k_s2s, dim3(NB), dim3(256), 0, stream,
                           hcur, gst, qstar, hl, cl, lWih, lWhh, lbih, lbhh, ebuf);

    hipLaunchKernelGGL(k_out, dim3(1), dim3(64), 0, stream, qstar, Wout, bout, out);
    (void)in_sizes; (void)n_in; (void)out_size;
}

// Round 5
// 4597.810 us; speedup vs baseline: 3.3936x; 1.2088x over previous
//
#include <hip/hip_runtime.h>
#include <hip/hip_bf16.h>

#define NN 20000   // nodes
#define NE 320000  // edges
#define NB 64      // graphs
#define DIN 16
#define DE 8
#define HE 128
#define D 32
#define TST 8
#define S2S 12

typedef __attribute__((ext_vector_type(8))) short short8x;   // 8 bf16 = 4 VGPRs (MFMA A/B frag)
typedef __attribute__((ext_vector_type(4))) float f32x4;     // MFMA C/D frag

__device__ __forceinline__ float sigf(float x) { return 1.f / (1.f + expf(-x)); }

__device__ __forceinline__ void split_bf16(float x, unsigned short& hi, unsigned short& lo) {
    __hip_bfloat16 h = __float2bfloat16(x);
    hi = *(unsigned short*)&h;
    float r = x - __bfloat162float(h);
    __hip_bfloat16 l = __float2bfloat16(r);
    lo = *(unsigned short*)&l;
}

// -------- graph segment starts: start[b] = lower_bound(batch, b), start[NB]=NN
__global__ void k_graph_start(const int* __restrict__ batch, int* __restrict__ start) {
    int b = threadIdx.x;
    if (b > NB) return;
    int lo = 0, hi = NN;
    while (lo < hi) {
        int mid = (lo + hi) >> 1;
        if (batch[mid] < b) lo = mid + 1; else hi = mid;
    }
    start[b] = lo;
}

// -------- Wt[k][f][d] = We2[k][d*32+f] (k<128), row 128 = be2; split hi/lo bf16
__global__ __launch_bounds__(256) void k_prep_w(
    const float* __restrict__ We2, const float* __restrict__ be2,
    unsigned short* __restrict__ wth, unsigned short* __restrict__ wtl) {
    int idx = blockIdx.x * 256 + threadIdx.x;  // = k*1024 + f*32 + d
    if (idx >= 129 * 1024) return;
    int k = idx >> 10, rem = idx & 1023, f = rem >> 5, d = rem & 31;
    float v = (k < 128) ? We2[k * 1024 + d * 32 + f] : be2[d * 32 + f];
    unsigned short hi, lo;
    split_bf16(v, hi, lo);
    wth[idx] = hi;
    wtl[idx] = lo;
}

// -------- z precompute (once per launch; z depends only on edge_data):
// zb[k][e] = relu(ed[e] @ We1[:,k] + be1[k]), k-major for coalesced per-k reads
__global__ __launch_bounds__(256) void k_prep_z(
    const float* __restrict__ ed, const float* __restrict__ We1,
    const float* __restrict__ be1, float* __restrict__ zb) {
    const int tid = threadIdx.x;
    const int e = blockIdx.x * 256 + tid;
    __shared__ float we1s[DE * HE];
    __shared__ float be1s[HE];
    for (int i = tid; i < DE * HE; i += 256) we1s[i] = We1[i];
    if (tid < HE) be1s[tid] = be1[tid];
    const float4 v0 = *(const float4*)(ed + (size_t)e * 8);
    const float4 v1 = *(const float4*)(ed + (size_t)e * 8 + 4);
    __syncthreads();
    float edr[8];
    edr[0] = v0.x; edr[1] = v0.y; edr[2] = v0.z; edr[3] = v0.w;
    edr[4] = v1.x; edr[5] = v1.y; edr[6] = v1.z; edr[7] = v1.w;
    for (int k = 0; k < 128; ++k) {
        float acc = be1s[k];
#pragma unroll
        for (int j = 0; j < 8; ++j) acc += edr[j] * we1s[j * HE + k];
        zb[(size_t)k * NE + e] = fmaxf(acc, 0.f);
    }
}

// -------- h0 = x @ W_in + b_in  (+ optional bf16 hi/lo split emit)
__global__ __launch_bounds__(256) void k_input_linear(
    const float* __restrict__ x, const float* __restrict__ Win,
    const float* __restrict__ bin, float* __restrict__ h,
    unsigned short* __restrict__ hhi, unsigned short* __restrict__ hlo) {
    int idx = blockIdx.x * 256 + threadIdx.x;  // n*32+f, grid exact
    int n = idx >> 5, f = idx & 31;
    float acc = bin[f];
#pragma unroll
    for (int d = 0; d < DIN; ++d) acc += x[n * DIN + d] * Win[d * D + f];
    h[idx] = acc;
    if (hhi) {
        unsigned short hi, lo;
        split_bf16(acc, hi, lo);
        hhi[idx] = hi;
        hlo[idx] = lo;
    }
}

// -------- MFMA msg v3: block = 256 edges (4 waves x 64 edges, 4 e-tiles/wave).
// W staged global->LDS per 8-k chunk (2-barrier K-loop, 32 KB); W-frags read
// from LDS once per k and reused across 4 e-tiles (24 MFMA per 4 ds_read_b128).
// z precomputed in zb[128][NE]; zk applied per-k in fp32 (bit-identical math).
__global__ __launch_bounds__(256) void k_msg_mfma3(
    const float* __restrict__ zb,
    const unsigned short* __restrict__ wth, const unsigned short* __restrict__ wtl,
    const unsigned short* __restrict__ hhi, const unsigned short* __restrict__ hlo,
    const int* __restrict__ src, const int* __restrict__ dst,
    float* __restrict__ agg) {
    const int tid = threadIdx.x;
    const int e0 = blockIdx.x * 256;

    __shared__ unsigned short wlds[16384];  // 32 KB: [0..8192) hi chunk, [8192..) lo

    const int lane = tid & 63;
    const int wv = tid >> 6;
    const int eidx = lane & 15;
    const int quad = lane >> 4;
    const int d0 = quad * 8;
    const int fo = eidx * 32 + d0;  // element offset of frag within a 1024-el k-row

    // prologue: issue chunk-0 staging loads (16 KB hi + 16 KB lo, 64 B/thread each)
    uint4 sh[4], sl[4];
#pragma unroll
    for (int r = 0; r < 4; ++r) {
        sh[r] = *(const uint4*)(wth + r * 2048 + tid * 8);
        sl[r] = *(const uint4*)(wtl + r * 2048 + tid * 8);
    }

    // per-e-tile state: edge ids, B-frags (h hi/lo), z row offsets
    int eoff[4];
    short8x bhi[4], blo[4];
#pragma unroll
    for (int et = 0; et < 4; ++et) {
        const int e = e0 + wv * 64 + et * 16 + eidx;
        eoff[et] = e;
        const int sn = src[e];
        const size_t hb = (size_t)sn * 32 + d0;
        bhi[et] = *(const short8x*)(hhi + hb);
        blo[et] = *(const short8x*)(hlo + hb);
    }
    float zcur[4];
#pragma unroll
    for (int et = 0; et < 4; ++et) zcur[et] = zb[eoff[et]];  // k = 0

    f32x4 macc[4][2];
#pragma unroll
    for (int et = 0; et < 4; ++et) {
        macc[et][0] = (f32x4){0.f, 0.f, 0.f, 0.f};
        macc[et][1] = (f32x4){0.f, 0.f, 0.f, 0.f};
    }

    for (int c = 0; c < 16; ++c) {
        __syncthreads();  // previous chunk's LDS consumers done
#pragma unroll
        for (int r = 0; r < 4; ++r) {
            *(uint4*)&wlds[r * 2048 + tid * 8] = sh[r];
            *(uint4*)&wlds[8192 + r * 2048 + tid * 8] = sl[r];
        }
        __syncthreads();
        if (c < 15) {  // stage next chunk while computing this one
            const size_t g0 = (size_t)(c + 1) * 8192;
#pragma unroll
            for (int r = 0; r < 4; ++r) {
                sh[r] = *(const uint4*)(wth + g0 + r * 2048 + tid * 8);
                sl[r] = *(const uint4*)(wtl + g0 + r * 2048 + tid * 8);
            }
        }
#pragma unroll
        for (int m = 0; m < 8; ++m) {
            const int k = c * 8 + m;
            float zk[4];
#pragma unroll
            for (int et = 0; et < 4; ++et) zk[et] = zcur[et];
            if (k < 127) {
                const size_t zrow = (size_t)(k + 1) * NE;
#pragma unroll
                for (int et = 0; et < 4; ++et) zcur[et] = zb[zrow + eoff[et]];
            }
            // W-frags for this k (shared across the wave's 4 e-tiles)
            const int mb = m * 1024 + fo;
            const short8x fh0 = *(const short8x*)&wlds[mb];
            const short8x fh1 = *(const short8x*)&wlds[mb + 512];
            const short8x fl0 = *(const short8x*)&wlds[8192 + mb];
            const short8x fl1 = *(const short8x*)&wlds[8192 + mb + 512];
#pragma unroll
            for (int et = 0; et < 4; ++et) {
                f32x4 t0 = {0.f, 0.f, 0.f, 0.f}, t1 = {0.f, 0.f, 0.f, 0.f};
                t0 = __builtin_amdgcn_mfma_f32_16x16x32_bf16(fh0, bhi[et], t0, 0, 0, 0);
                t1 = __builtin_amdgcn_mfma_f32_16x16x32_bf16(fh1, bhi[et], t1, 0, 0, 0);
                t0 = __builtin_amdgcn_mfma_f32_16x16x32_bf16(fl0, bhi[et], t0, 0, 0, 0);
                t1 = __builtin_amdgcn_mfma_f32_16x16x32_bf16(fl1, bhi[et], t1, 0, 0, 0);
                t0 = __builtin_amdgcn_mfma_f32_16x16x32_bf16(fh0, blo[et], t0, 0, 0, 0);
                t1 = __builtin_amdgcn_mfma_f32_16x16x32_bf16(fh1, blo[et], t1, 0, 0, 0);
                macc[et][0] += zk[et] * t0;
                macc[et][1] += zk[et] * t1;
            }
        }
    }

    {   // k = 128: be2 virtual row, z == 1; frags direct from global (once)
        const unsigned short* bh = wth + 128 * 1024;
        const unsigned short* bl = wtl + 128 * 1024;
        const short8x fh0 = *(const short8x*)(bh + fo);
        const short8x fh1 = *(const short8x*)(bh + fo + 512);
        const short8x fl0 = *(const short8x*)(bl + fo);
        const short8x fl1 = *(const short8x*)(bl + fo + 512);
#pragma unroll
        for (int et = 0; et < 4; ++et) {
            f32x4 t0 = {0.f, 0.f, 0.f, 0.f}, t1 = {0.f, 0.f, 0.f, 0.f};
            t0 = __builtin_amdgcn_mfma_f32_16x16x32_bf16(fh0, bhi[et], t0, 0, 0, 0);
            t1 = __builtin_amdgcn_mfma_f32_16x16x32_bf16(fh1, bhi[et], t1, 0, 0, 0);
            t0 = __builtin_amdgcn_mfma_f32_16x16x32_bf16(fl0, bhi[et], t0, 0, 0, 0);
            t1 = __builtin_amdgcn_mfma_f32_16x16x32_bf16(fl1, bhi[et], t1, 0, 0, 0);
            t0 = __builtin_amdgcn_mfma_f32_16x16x32_bf16(fh0, blo[et], t0, 0, 0, 0);
            t1 = __builtin_amdgcn_mfma_f32_16x16x32_bf16(fh1, blo[et], t1, 0, 0, 0);
            macc[et][0] += t0;
            macc[et][1] += t1;
        }
    }

    // epilogue: lane holds msg^T rows f = tile*16 + quad*4 + r, col = edge
#pragma unroll
    for (int et = 0; et < 4; ++et) {
        const int dn = dst[eoff[et]];
        float* ap = agg + (size_t)dn * 32 + quad * 4;
        atomicAdd(ap + 0, macc[et][0].x);
        atomicAdd(ap + 1, macc[et][0].y);
        atomicAdd(ap + 2, macc[et][0].z);
        atomicAdd(ap + 3, macc[et][0].w);
        atomicAdd(ap + 16 + 0, macc[et][1].x);
        atomicAdd(ap + 16 + 1, macc[et][1].y);
        atomicAdd(ap + 16 + 2, macc[et][1].z);
        atomicAdd(ap + 16 + 3, macc[et][1].w);
    }
}

// -------- MFMA msg v2 (proven R4 fallback): ring prefetch, z in regs + shfl
#define LDFRAG(slot, kk)                                          \
    do {                                                          \
        const unsigned short* _ph = wth + ((size_t)(kk) << 10);   \
        const unsigned short* _pl = wtl + ((size_t)(kk) << 10);   \
        ring[slot][0] = *(const short8x*)(_ph + b0);              \
        ring[slot][1] = *(const short8x*)(_ph + b1);              \
        ring[slot][2] = *(const short8x*)(_pl + b0);              \
        ring[slot][3] = *(const short8x*)(_pl + b1);              \
    } while (0)

__global__ __launch_bounds__(256) void k_msg_mfma(
    const float* __restrict__ ed, const float* __restrict__ We1,
    const float* __restrict__ be1,
    const unsigned short* __restrict__ wth, const unsigned short* __restrict__ wtl,
    const unsigned short* __restrict__ hhi, const unsigned short* __restrict__ hlo,
    const int* __restrict__ src, const int* __restrict__ dst,
    float* __restrict__ agg) {
    const int tid = threadIdx.x;
    const int e0 = blockIdx.x * 64;

    __shared__ float we1s[DE * HE];
    __shared__ float be1s[HE];

    for (int i = tid; i < DE * HE; i += 256) we1s[i] = We1[i];
    if (tid < HE) be1s[tid] = be1[tid];

    const int lane = tid & 63;
    const int wv = tid >> 6;
    const int eidx = lane & 15;
    const int quad = lane >> 4;
    const int eloc = wv * 16 + eidx;
    const int e = e0 + eloc;
    const int d0 = quad * 8;

    const int sn = src[e];
    const int dn = dst[e];

    const int b0 = eidx * 32 + d0;
    const int b1 = b0 + 16 * 32;

    const size_t hb = (size_t)sn * 32 + d0;
    const short8x bhi = *(const short8x*)(hhi + hb);
    const short8x blo = *(const short8x*)(hlo + hb);
    const float4 edv0 = *(const float4*)(ed + (size_t)e * 8);
    const float4 edv1 = *(const float4*)(ed + (size_t)e * 8 + 4);

    short8x ring[4][4];
    LDFRAG(0, 0);
    LDFRAG(1, 1);
    LDFRAG(2, 2);

    __syncthreads();

    float edr[8];
    edr[0] = edv0.x; edr[1] = edv0.y; edr[2] = edv0.z; edr[3] = edv0.w;
    edr[4] = edv1.x; edr[5] = edv1.y; edr[6] = edv1.z; edr[7] = edv1.w;
    float zreg[32];
#pragma unroll
    for (int m = 0; m < 32; ++m) {
        const int kk = (quad << 5) + m;
        float acc = be1s[kk];
#pragma unroll
        for (int j = 0; j < 8; ++j) acc += edr[j] * we1s[j * 128 + kk];
        zreg[m] = fmaxf(acc, 0.f);
    }

    f32x4 m0 = {0.f, 0.f, 0.f, 0.f}, m1 = {0.f, 0.f, 0.f, 0.f};

    for (int q = 0; q < 4; ++q) {
        const int bsrc = q * 16 + eidx;
#pragma unroll
        for (int m = 0; m < 32; ++m) {
            const int k = q * 32 + m;
            const int slot = m & 3;
            const int pslot = (m + 3) & 3;
            int kn = k + 3;
            kn = (kn > 128) ? 128 : kn;
            LDFRAG(pslot, kn);

            const float zk = __shfl(zreg[m], bsrc);

            f32x4 t0 = {0.f, 0.f, 0.f, 0.f}, t1 = {0.f, 0.f, 0.f, 0.f};
            t0 = __builtin_amdgcn_mfma_f32_16x16x32_bf16(ring[slot][0], bhi, t0, 0, 0, 0);
            t1 = __builtin_amdgcn_mfma_f32_16x16x32_bf16(ring[slot][1], bhi, t1, 0, 0, 0);
            t0 = __builtin_amdgcn_mfma_f32_16x16x32_bf16(ring[slot][2], bhi, t0, 0, 0, 0);
            t1 = __builtin_amdgcn_mfma_f32_16x16x32_bf16(ring[slot][3], bhi, t1, 0, 0, 0);
            t0 = __builtin_amdgcn_mfma_f32_16x16x32_bf16(ring[slot][0], blo, t0, 0, 0, 0);
            t1 = __builtin_amdgcn_mfma_f32_16x16x32_bf16(ring[slot][1], blo, t1, 0, 0, 0);

            m0 += zk * t0;
            m1 += zk * t1;
        }
    }
    {
        f32x4 t0 = {0.f, 0.f, 0.f, 0.f}, t1 = {0.f, 0.f, 0.f, 0.f};
        t0 = __builtin_amdgcn_mfma_f32_16x16x32_bf16(ring[0][0], bhi, t0, 0, 0, 0);
        t1 = __builtin_amdgcn_mfma_f32_16x16x32_bf16(ring[0][1], bhi, t1, 0, 0, 0);
        t0 = __builtin_amdgcn_mfma_f32_16x16x32_bf16(ring[0][2], bhi, t0, 0, 0, 0);
        t1 = __builtin_amdgcn_mfma_f32_16x16x32_bf16(ring[0][3], bhi, t1, 0, 0, 0);
        t0 = __builtin_amdgcn_mfma_f32_16x16x32_bf16(ring[0][0], blo, t0, 0, 0, 0);
        t1 = __builtin_amdgcn_mfma_f32_16x16x32_bf16(ring[0][1], blo, t1, 0, 0, 0);
        m0 += t0;
        m1 += t1;
    }

    float* ap = agg + (size_t)dn * 32 + quad * 4;
    atomicAdd(ap + 0, m0.x);
    atomicAdd(ap + 1, m0.y);
    atomicAdd(ap + 2, m0.z);
    atomicAdd(ap + 3, m0.w);
    atomicAdd(ap + 16 + 0, m1.x);
    atomicAdd(ap + 16 + 1, m1.y);
    atomicAdd(ap + 16 + 2, m1.z);
    atomicAdd(ap + 16 + 3, m1.w);
}

// -------- fallback (proven R2 path): recompute z per edge, fp32 VALU bilinear
__global__ __launch_bounds__(256) void k_msg_fused(
    const float* __restrict__ ed, const float* __restrict__ We1,
    const float* __restrict__ be1, const float* __restrict__ We2,
    const float* __restrict__ h, const int* __restrict__ src,
    const int* __restrict__ dst, float* __restrict__ agg) {
    const int tid = threadIdx.x;
    const int e0 = blockIdx.x * 64;
    __shared__ float we1s[DE * HE];
    __shared__ float be1s[HE];
    __shared__ float eds[64][9];
    __shared__ float zs[HE][64];
    __shared__ float hs[64][33];
    __shared__ float ws2s[4][1024];
    __shared__ int srcs[64];

    for (int i = tid; i < DE * HE; i += 256) we1s[i] = We1[i];
    if (tid < HE) be1s[tid] = be1[tid];
    if (tid < 64) srcs[tid] = src[e0 + tid];
    for (int i = tid; i < 64 * DE; i += 256) eds[i >> 3][i & 7] = ed[(size_t)e0 * DE + i];
    __syncthreads();

    {
        const int e = tid & 63, kb = tid >> 6;
        float edr[8];
#pragma unroll
        for (int j = 0; j < 8; ++j) edr[j] = eds[e][j];
        for (int m = 0; m < 32; ++m) {
            const int k = kb * 32 + m;
            float acc = be1s[k];
#pragma unroll
            for (int j = 0; j < 8; ++j) acc += edr[j] * we1s[j * HE + k];
            zs[k][e] = fmaxf(acc, 0.f);
        }
    }
    for (int i = tid; i < 64 * 32; i += 256) {
        const int e = i >> 5, d = i & 31;
        hs[e][d] = h[(size_t)srcs[e] * D + d];
    }
    __syncthreads();

    const int ep = tid & 31, fg = tid >> 5;
    float hr[2][32];
#pragma unroll
    for (int d = 0; d < 32; ++d) {
        hr[0][d] = hs[ep * 2][d];
        hr[1][d] = hs[ep * 2 + 1][d];
    }
    float acc[2][4];
#pragma unroll
    for (int i = 0; i < 2; ++i)
#pragma unroll
        for (int j = 0; j < 4; ++j) acc[i][j] = 0.f;

    for (int kc = 0; kc < 32; ++kc) {
        __syncthreads();
#pragma unroll
        for (int r = 0; r < 4; ++r) {
            const int idx4 = tid + 256 * r;
            const int kr = idx4 >> 8, c4 = idx4 & 255;
            *(float4*)&ws2s[kr][c4 * 4] =
                *(const float4*)(We2 + (size_t)(kc * 4 + kr) * 1024 + c4 * 4);
        }
        __syncthreads();
#pragma unroll
        for (int kk = 0; kk < 4; ++kk) {
            const int k = kc * 4 + kk;
            const float z0 = zs[k][ep * 2], z1 = zs[k][ep * 2 + 1];
#pragma unroll
            for (int d = 0; d < 32; ++d) {
                const float4 w4 = *(const float4*)&ws2s[kk][d * 32 + fg * 4];
                const float c0 = z0 * hr[0][d], c1 = z1 * hr[1][d];
                acc[0][0] += c0 * w4.x; acc[0][1] += c0 * w4.y;
                acc[0][2] += c0 * w4.z; acc[0][3] += c0 * w4.w;
                acc[1][0] += c1 * w4.x; acc[1][1] += c1 * w4.y;
                acc[1][2] += c1 * w4.z; acc[1][3] += c1 * w4.w;
            }
        }
    }
#pragma unroll
    for (int i = 0; i < 2; ++i) {
        const int e = e0 + ep * 2 + i;
        float* ap = &agg[(size_t)dst[e] * D + fg * 4];
#pragma unroll
        for (int j = 0; j < 4; ++j) atomicAdd(ap + j, acc[i][j]);
    }
}

// -------- GRU cell per node (8 nodes x 32 f per block) (+ optional split emit)
__global__ __launch_bounds__(256) void k_gru(
    const float* __restrict__ h, const float* __restrict__ agg,
    const float* __restrict__ Wroot, const float* __restrict__ bconv,
    const float* __restrict__ Wih, const float* __restrict__ Whh,
    const float* __restrict__ bih, const float* __restrict__ bhh,
    float* __restrict__ hout,
    unsigned short* __restrict__ hhi, unsigned short* __restrict__ hlo) {
    const int idx = blockIdx.x * 256 + threadIdx.x;  // grid exact: NN*D/256
    const int n = idx >> 5, f = idx & 31, nl = threadIdx.x >> 5;
    __shared__ float hsh[8][33], msh[8][33];
    const float hv = h[n * D + f];
    hsh[nl][f] = hv;
    __syncthreads();
    float m = bconv[f] + agg[n * D + f];
#pragma unroll
    for (int d = 0; d < 32; ++d) m += hsh[nl][d] * Wroot[d * D + f];
    m = fmaxf(m, 0.f);
    msh[nl][f] = m;
    __syncthreads();
    float gir = bih[f], giz = bih[D + f], gin = bih[2 * D + f];
    float ghr = bhh[f], ghz = bhh[D + f], ghn = bhh[2 * D + f];
#pragma unroll
    for (int d = 0; d < 32; ++d) {
        const float md = msh[nl][d], hd = hsh[nl][d];
        gir += md * Wih[f * D + d];
        giz += md * Wih[(D + f) * D + d];
        gin += md * Wih[(2 * D + f) * D + d];
        ghr += hd * Whh[f * D + d];
        ghz += hd * Whh[(D + f) * D + d];
        ghn += hd * Whh[(2 * D + f) * D + d];
    }
    const float r = sigf(gir + ghr);
    const float z = sigf(giz + ghz);
    const float nn2 = tanhf(gin + r * ghn);
    const float ho = (1.f - z) * nn2 + z * hv;
    hout[n * D + f] = ho;
    if (hhi) {
        unsigned short hi, lo;
        split_bf16(ho, hi, lo);
        hhi[idx] = hi;
        hlo[idx] = lo;
    }
}

// -------- one Set2Set step: LSTM cell + segment softmax attention, block = graph
__global__ __launch_bounds__(256) void k_s2s(
    const float* __restrict__ h, const int* __restrict__ start,
    float* __restrict__ qstar, float* __restrict__ hl, float* __restrict__ cl,
    const float* __restrict__ Wih, const float* __restrict__ Whh,
    const float* __restrict__ bih, const float* __restrict__ bhh,
    float* __restrict__ ebuf) {
    const int b = blockIdx.x, t = threadIdx.x;
    __shared__ float qst[64], hls[32], gates[128], qs[32];
    __shared__ float red[256];
    __shared__ float rsum[8][33];
    if (t < 64) qst[t] = qstar[b * 64 + t];
    if (t < 32) hls[t] = hl[b * 32 + t];
    __syncthreads();
    if (t < 128) {
        float g = bih[t] + bhh[t];
#pragma unroll 8
        for (int j = 0; j < 64; ++j) g += qst[j] * Wih[t * 64 + j];
#pragma unroll 8
        for (int j = 0; j < 32; ++j) g += hls[j] * Whh[t * 32 + j];
        gates[t] = g;
    }
    __syncthreads();
    if (t < 32) {  // i,f,g,o order
        const float ig = sigf(gates[t]);
        const float fg = sigf(gates[32 + t]);
        const float gg = tanhf(gates[64 + t]);
        const float og = sigf(gates[96 + t]);
        const float c = fg * cl[b * 32 + t] + ig * gg;
        const float q = og * tanhf(c);
        cl[b * 32 + t] = c;
        hl[b * 32 + t] = q;
        qstar[b * 64 + t] = q;
        qs[t] = q;
    }
    __syncthreads();
    const int s0 = start[b], s1 = start[b + 1];
    float lmax = -3.4e38f;
    for (int n = s0 + t; n < s1; n += 256) {
        const float4* hv = (const float4*)(h + (size_t)n * D);
        float e = 0.f;
#pragma unroll
        for (int u = 0; u < 8; ++u) {
            const float4 v = hv[u];
            e += v.x * qs[u * 4] + v.y * qs[u * 4 + 1] + v.z * qs[u * 4 + 2] + v.w * qs[u * 4 + 3];
        }
        ebuf[n] = e;
        lmax = fmaxf(lmax, e);
    }
    red[t] = lmax;
    __syncthreads();
    for (int s = 128; s > 0; s >>= 1) {
        if (t < s) red[t] = fmaxf(red[t], red[t + s]);
        __syncthreads();
    }
    const float smax = red[0];
    __syncthreads();
    float lsum = 0.f;
    for (int n = s0 + t; n < s1; n += 256) {
        const float w = expf(ebuf[n] - smax);
        ebuf[n] = w;
        lsum += w;
    }
    red[t] = lsum;
    __syncthreads();
    for (int s = 128; s > 0; s >>= 1) {
        if (t < s) red[t] += red[t + s];
        __syncthreads();
    }
    const float den = red[0];
    const float inv = (den > 0.f) ? 1.f / den : 0.f;
    const int fl = t & 31, sl = t >> 5;
    float racc = 0.f;
    for (int n = s0 + sl; n < s1; n += 8) racc += ebuf[n] * h[(size_t)n * D + fl];
    rsum[sl][fl] = racc;
    __syncthreads();
    if (sl == 0) {
        float rv = 0.f;
#pragma unroll
        for (int u = 0; u < 8; ++u) rv += rsum[u][fl];
        qstar[b * 64 + 32 + fl] = rv * inv;
    }
}

// -------- out = q_star @ W_out + b_out
__global__ void k_out(const float* __restrict__ qstar, const float* __restrict__ Wout,
                      const float* __restrict__ bout, float* __restrict__ out) {
    int b = threadIdx.x;
    if (b < NB) {
        float acc = bout[0];
#pragma unroll 8
        for (int j = 0; j < 64; ++j) acc += qstar[b * 64 + j] * Wout[j];
        out[b] = acc;
    }
}

extern "C" void kernel_launch(void* const* d_in, const int* in_sizes, int n_in,
                              void* d_out, int out_size, void* d_ws, size_t ws_size,
                              hipStream_t stream) {
    const float* x     = (const float*)d_in[0];
    // d_in[1] adj unused; d_in[2] T == 8 (module constant)
    const float* ed    = (const float*)d_in[3];
    const int*   edges = (const int*)d_in[4];
    const int*   batch = (const int*)d_in[5];
    const float* Wi    = (const float*)d_in[6];
    const float* bi    = (const float*)d_in[7];
    const float* We1   = (const float*)d_in[8];
    const float* be1   = (const float*)d_in[9];
    const float* We2   = (const float*)d_in[10];
    const float* be2   = (const float*)d_in[11];
    const float* Wroot = (const float*)d_in[12];
    const float* bconv = (const float*)d_in[13];
    const float* gWih  = (const float*)d_in[14];
    const float* gWhh  = (const float*)d_in[15];
    const float* gbih  = (const float*)d_in[16];
    const float* gbhh  = (const float*)d_in[17];
    const float* lWih  = (const float*)d_in[18];
    const float* lWhh  = (const float*)d_in[19];
    const float* lbih  = (const float*)d_in[20];
    const float* lbhh  = (const float*)d_in[21];
    const float* Wout  = (const float*)d_in[22];
    const float* bout  = (const float*)d_in[23];
    float* out = (float*)d_out;

    const int* srcp = edges;
    const int* dstp = edges + NE;

    char* ws = (char*)d_ws;
    size_t off = 0;
    auto alloc = [&](size_t bytes) -> char* {
        char* p = ws + off;
        off += (bytes + 255) & ~(size_t)255;
        return p;
    };
    float* hA    = (float*)alloc((size_t)NN * D * 4);
    float* hB    = (float*)alloc((size_t)NN * D * 4);
    float* agg   = (float*)alloc((size_t)NN * D * 4);
    float* ebuf  = (float*)alloc((size_t)NN * 4);
    float* qstar = (float*)alloc((size_t)NB * 64 * 4);  // qstar,hl,cl contiguous
    float* hl    = (float*)alloc((size_t)NB * 32 * 4);
    float* cl    = (float*)alloc((size_t)NB * 32 * 4);
    int*   gst   = (int*)alloc((NB + 1) * 4);
    // MFMA-path extras (~5.6 MB)
    unsigned short* hhiA = (unsigned short*)alloc((size_t)NN * D * 2);
    unsigned short* hloA = (unsigned short*)alloc((size_t)NN * D * 2);
    unsigned short* hhiB = (unsigned short*)alloc((size_t)NN * D * 2);
    unsigned short* hloB = (unsigned short*)alloc((size_t)NN * D * 2);
    unsigned short* wth  = (unsigned short*)alloc((size_t)129 * 1024 * 2);
    unsigned short* wtl  = (unsigned short*)alloc((size_t)129 * 1024 * 2);
    const size_t base_off = off;
    const bool mfma_path = (ws_size >= base_off);
    // v3 extra: precomputed z, k-major [128][NE] fp32 (~164 MB)
    float* zb = (float*)alloc((size_t)128 * NE * 4);
    const bool mfma3_path = (ws_size >= off);

    hipLaunchKernelGGL(k_graph_start, dim3(1), dim3(128), 0, stream, batch, gst);
    hipLaunchKernelGGL(k_input_linear, dim3(NN * D / 256), dim3(256), 0, stream, x, Wi, bi, hA,
                       mfma_path ? hhiA : (unsigned short*)nullptr,
                       mfma_path ? hloA : (unsigned short*)nullptr);
    if (mfma_path)
        hipLaunchKernelGGL(k_prep_w, dim3((129 * 1024 + 255) / 256), dim3(256), 0, stream,
                           We2, be2, wth, wtl);
    if (mfma3_path)
        hipLaunchKernelGGL(k_prep_z, dim3(NE / 256), dim3(256), 0, stream, ed, We1, be1, zb);
    hipMemsetAsync(qstar, 0, (size_t)(NB * 64 + NB * 32 + NB * 32) * 4, stream);

    float* hcur = hA;
    float* hnxt = hB;
    unsigned short *hhic = hhiA, *hloc = hloA, *hhin = hhiB, *hlon = hloB;
    for (int t = 0; t < TST; ++t) {
        hipMemsetAsync(agg, 0, (size_t)NN * D * 4, stream);
        if (mfma3_path)
            hipLaunchKernelGGL(k_msg_mfma3, dim3(NE / 256), dim3(256), 0, stream,
                               zb, wth, wtl, hhic, hloc, srcp, dstp, agg);
        else if (mfma_path)
            hipLaunchKernelGGL(k_msg_mfma, dim3(NE / 64), dim3(256), 0, stream,
                               ed, We1, be1, wth, wtl, hhic, hloc, srcp, dstp, agg);
        else
            hipLaunchKernelGGL(k_msg_fused, dim3(NE / 64), dim3(256), 0, stream,
                               ed, We1, be1, We2, hcur, srcp, dstp, agg);
        hipLaunchKernelGGL(k_gru, dim3(NN * D / 256), dim3(256), 0, stream,
                           hcur, agg, Wroot, bconv, gWih, gWhh, gbih, gbhh, hnxt,
                           mfma_path ? hhin : (unsigned short*)nullptr,
                           mfma_path ? hlon : (unsigned short*)nullptr);
        float* tf = hcur; hcur = hnxt; hnxt = tf;
        unsigned short* ts;
        ts = hhic; hhic = hhin; hhin = ts;
        ts = hloc; hloc = hlon; hlon = ts;
    }

    for (int s = 0; s < S2S; ++s)
        hipLaunchKernelGGL(k_s2s, dim3(NB), dim3(256), 0, stream,
                           hcur, gst, qstar, hl, cl, lWih, lWhh, lbih, lbhh, ebuf);

    hipLaunchKernelGGL(k_out, dim3(1), dim3(64), 0, stream, qstar, Wout, bout, out);
    (void)in_sizes; (void)n_in; (void)out_size;
}